// Round 2
// baseline (211.342 us; speedup 1.0000x reference)
//
#include <hip/hip_runtime.h>
#include <hip/hip_bf16.h>

typedef __attribute__((ext_vector_type(8))) short short8;
typedef __attribute__((ext_vector_type(4))) float f32x4;

#define MFMA16(A, B, C) __builtin_amdgcn_mfma_f32_16x16x32_bf16((A), (B), (C), 0, 0, 0)

__device__ __forceinline__ unsigned short bfbits(float f) {
  return __builtin_bit_cast(unsigned short, (__bf16)f);
}

constexpr int BH = 16;
constexpr int Mn = 2048;
constexpr int Dn = 64;
constexpr int LIMn = 2048;
constexpr int PEROWS = 2112;  // 2048 + 64 zero pad for diagonal-tile overread

// ---------------- prep kernels: fp32 -> bf16 (+ transposes) into d_ws ----------------

__global__ void prep_k(const float* __restrict__ K, unsigned short* __restrict__ Kbf) {
  int idx = (blockIdx.x * 256 + threadIdx.x) * 8;
  const float4* p = (const float4*)(K + idx);
  float4 f0 = p[0], f1 = p[1];
  short8 u;
  u[0]=(short)bfbits(f0.x); u[1]=(short)bfbits(f0.y); u[2]=(short)bfbits(f0.z); u[3]=(short)bfbits(f0.w);
  u[4]=(short)bfbits(f1.x); u[5]=(short)bfbits(f1.y); u[6]=(short)bfbits(f1.z); u[7]=(short)bfbits(f1.w);
  *(short8*)&Kbf[idx] = u;
}

__global__ void prep_vt(const float* __restrict__ V, unsigned short* __restrict__ Vt) {
  __shared__ float tile[64][65];
  const int bh = blockIdx.x & 15, lt = blockIdx.x >> 4;
  const int l0 = lt * 64;
  const float* Vb = V + (size_t)bh * Mn * Dn;
  const int t = threadIdx.x;
  {
    const int lr = t >> 2, dc = (t & 3) * 16;
    const float4* p = (const float4*)(Vb + (size_t)(l0 + lr) * Dn + dc);
#pragma unroll
    for (int i = 0; i < 4; ++i) {
      float4 f = p[i];
      tile[dc + 4 * i + 0][lr] = f.x;
      tile[dc + 4 * i + 1][lr] = f.y;
      tile[dc + 4 * i + 2][lr] = f.z;
      tile[dc + 4 * i + 3][lr] = f.w;
    }
  }
  __syncthreads();
  {
    const int dr = t >> 2, lc = (t & 3) * 16;
    unsigned short* dst = Vt + (size_t)bh * Dn * Mn + (size_t)dr * Mn + l0 + lc;
#pragma unroll
    for (int h = 0; h < 2; ++h) {
      short8 u;
#pragma unroll
      for (int j = 0; j < 8; ++j) u[j] = (short)bfbits(tile[dr][lc + h * 8 + j]);
      *(short8*)&dst[h * 8] = u;
    }
  }
}

__global__ void prep_pet(const float* __restrict__ PE, unsigned short* __restrict__ PEt) {
  __shared__ float tile[64][65];
  const int c0 = blockIdx.x * 64;
  const int t = threadIdx.x;
  {
    const int d = t >> 2, cc = (t & 3) * 16;
    const float* row = PE + (size_t)d * LIMn;
#pragma unroll
    for (int i = 0; i < 16; ++i) {
      int c = c0 + cc + i;
      tile[cc + i][d] = (c < LIMn) ? row[c] : 0.0f;
    }
  }
  __syncthreads();
  {
    const int cl = t >> 2, dc = (t & 3) * 16;
    unsigned short* dst = PEt + (size_t)(c0 + cl) * Dn + dc;
#pragma unroll
    for (int h = 0; h < 2; ++h) {
      short8 u;
#pragma unroll
      for (int j = 0; j < 8; ++j) u[j] = (short)bfbits(tile[cl][dc + h * 8 + j]);
      *(short8*)&dst[h * 8] = u;
    }
  }
}

// ---------------- main: 1 wave per block, no barriers, direct-from-L2 fragments ----------------

__launch_bounds__(64, 4)
__global__ void stair_attn_main(const float* __restrict__ Qg,
                                const unsigned short* __restrict__ Kbf,
                                const unsigned short* __restrict__ Vtb,
                                const unsigned short* __restrict__ PEt,
                                float* __restrict__ Og) {
  __shared__ __align__(16) unsigned short Plds[16 * 64];  // per-wave P bounce, swizzled

  const int lane = threadIdx.x;
  const int g = lane >> 4;
  const int q15 = lane & 15;

  const int bid = blockIdx.x;
  const int bh = bid & 15;          // head -> XCD locality (bid%8 == bh%8)
  const int jid = bid >> 4;         // 0..127
  const int mt = 31 - (jid >> 2);   // heavy blocks dispatched first
  const int slice = jid & 3;
  const int m0w = mt * 64 + slice * 16;

  const float* Qb = Qg + (size_t)bh * Mn * Dn;
  const unsigned short* Kb = Kbf + (size_t)bh * Mn * Dn;
  const unsigned short* Vb = Vtb + (size_t)bh * Dn * Mn;
  float* Ob = Og + (size_t)bh * Mn * Dn;

  // Q A-fragments (row = lane&15, k = g*8+j, +32 per s)
  short8 aq[2];
  {
    const float* qp = Qb + (size_t)(m0w + q15) * Dn;
#pragma unroll
    for (int s = 0; s < 2; ++s) {
      const float4* p = (const float4*)(qp + s * 32 + g * 8);
      float4 f0 = p[0], f1 = p[1];
      short8 a;
      a[0]=(short)bfbits(f0.x); a[1]=(short)bfbits(f0.y); a[2]=(short)bfbits(f0.z); a[3]=(short)bfbits(f0.w);
      a[4]=(short)bfbits(f1.x); a[5]=(short)bfbits(f1.y); a[6]=(short)bfbits(f1.z); a[7]=(short)bfbits(f1.w);
      aq[s] = a;
    }
  }

  float mrun[4], lrun[4];
  f32x4 o[4] = {};
#pragma unroll
  for (int r = 0; r < 4; ++r) { mrun[r] = -1e30f; lrun[r] = 0.0f; }

  for (int t = 0; t <= mt; ++t) {
    const int l0 = t * 64;
    const bool diag = (t == mt);
    const int ntmax = diag ? slice : 3;            // S col n-tiles needed
    const int u5cnt = (ntmax + 2 > 5) ? 5 : ntmax + 2;  // E band regs needed
    const int smax = diag ? (slice >> 1) : 1;      // PV k-halves needed
    const int cb0 = 2032 - m0w + l0;               // PEt row base (u = 15 - rw + li)

    // ---- issue all global fragment loads up front (L1/L2-hot)
    short8 kb[2][4], pe[2][5], vb[2][4];
#pragma unroll
    for (int s = 0; s < 2; ++s)
#pragma unroll
      for (int nt = 0; nt < 4; ++nt)
        if (nt <= ntmax)
          kb[s][nt] = *(const short8*)&Kb[(size_t)(l0 + nt * 16 + q15) * Dn + s * 32 + g * 8];
#pragma unroll
    for (int s = 0; s < 2; ++s)
#pragma unroll
      for (int u = 0; u < 5; ++u)
        if (u < u5cnt)
          pe[s][u] = *(const short8*)&PEt[(size_t)(cb0 + u * 16 + q15) * Dn + s * 32 + g * 8];
#pragma unroll
    for (int s = 0; s < 2; ++s)
      if (s <= smax)
#pragma unroll
        for (int nt = 0; nt < 4; ++nt)
          vb[s][nt] = *(const short8*)&Vb[(size_t)(nt * 16 + q15) * Mn + l0 + s * 32 + g * 8];

    // ---- QK^T (content scores)
    f32x4 qk[4] = {};
#pragma unroll
    for (int s = 0; s < 2; ++s)
#pragma unroll
      for (int nt = 0; nt < 4; ++nt)
        if (nt <= ntmax) qk[nt] = MFMA16(aq[s], kb[s][nt], qk[nt]);

    // ---- E = Q @ PEt band (cols u = 15 - rw + li, u in [0,79))
    f32x4 ev[5] = {};
#pragma unroll
    for (int s = 0; s < 2; ++s)
#pragma unroll
      for (int u = 0; u < 5; ++u)
        if (u < u5cnt) ev[u] = MFMA16(aq[s], pe[s][u], ev[u]);

    // ---- diagonal gather via in-register lane rotate:
    // E[rw][15-rw+li] lives at same g, same reg r, lane (q15+15-rw)&15,
    // register nt (q15<=rw) or nt+1 (q15>rw).
    float sv[4][4];
#pragma unroll
    for (int nt = 0; nt < 4; ++nt)
#pragma unroll
      for (int r = 0; r < 4; ++r) sv[nt][r] = -1e30f;
#pragma unroll
    for (int nt = 0; nt < 4; ++nt)
      if (nt <= ntmax) {
#pragma unroll
        for (int r = 0; r < 4; ++r) {
          const int rw = g * 4 + r;
          const int srcLane = (lane & 48) | ((q15 + 15 - rw) & 15);
          float e_lo = __shfl(ev[nt][r], srcLane, 64);
          float e_hi = __shfl(ev[nt + 1][r], srcLane, 64);
          float er = (q15 > rw) ? e_hi : e_lo;
          const int li = nt * 16 + q15;
          bool masked = diag && (li > slice * 16 + rw);
          sv[nt][r] = masked ? -1e30f : (qk[nt][r] + er) * 0.125f;
        }
      }

    // ---- online softmax (row rw spread over 16 lanes of group g)
    float mnew[4], alpha[4];
#pragma unroll
    for (int r = 0; r < 4; ++r) {
      float mx = fmaxf(fmaxf(sv[0][r], sv[1][r]), fmaxf(sv[2][r], sv[3][r]));
      mx = fmaxf(mx, __shfl_xor(mx, 1));
      mx = fmaxf(mx, __shfl_xor(mx, 2));
      mx = fmaxf(mx, __shfl_xor(mx, 4));
      mx = fmaxf(mx, __shfl_xor(mx, 8));
      float mn = fmaxf(mrun[r], mx);
      alpha[r] = exp2f((mrun[r] - mn) * 1.44269504f);
      mnew[r] = mn;
      mrun[r] = mn;
    }
    float pexp[4][4];
#pragma unroll
    for (int nt = 0; nt < 4; ++nt)
#pragma unroll
      for (int r = 0; r < 4; ++r)
        pexp[nt][r] = exp2f((sv[nt][r] - mnew[r]) * 1.44269504f);
#pragma unroll
    for (int r = 0; r < 4; ++r) {
      float sum = (pexp[0][r] + pexp[1][r]) + (pexp[2][r] + pexp[3][r]);
      sum += __shfl_xor(sum, 1);
      sum += __shfl_xor(sum, 2);
      sum += __shfl_xor(sum, 4);
      sum += __shfl_xor(sum, 8);
      lrun[r] = lrun[r] * alpha[r] + sum;
      o[0][r] *= alpha[r];
      o[1][r] *= alpha[r];
      o[2][r] *= alpha[r];
      o[3][r] *= alpha[r];
    }

    // ---- P (C/D layout) -> per-wave LDS -> A-fragments (same wave, no barrier)
#pragma unroll
    for (int nt = 0; nt < 4; ++nt)
#pragma unroll
      for (int r = 0; r < 4; ++r) {
        const int rw = g * 4 + r;
        Plds[(rw * 64 + nt * 16 + q15) ^ ((rw & 7) << 3)] = bfbits(pexp[nt][r]);
      }
    short8 pa[2];
#pragma unroll
    for (int s = 0; s < 2; ++s)
      if (s <= smax)
        pa[s] = *(short8*)&Plds[(q15 * 64 + s * 32 + g * 8) ^ ((q15 & 7) << 3)];

    // ---- PV
#pragma unroll
    for (int s = 0; s < 2; ++s)
      if (s <= smax)
#pragma unroll
        for (int nt = 0; nt < 4; ++nt)
          o[nt] = MFMA16(pa[s], vb[s][nt], o[nt]);
  }

  // ---- epilogue
#pragma unroll
  for (int nt = 0; nt < 4; ++nt)
#pragma unroll
    for (int r = 0; r < 4; ++r) {
      const int m = m0w + g * 4 + r;
      Ob[(size_t)m * Dn + nt * 16 + q15] = o[nt][r] / lrun[r];
    }
}

// ---------------- fallback (round-1 kernel, used only if ws too small) ----------------

constexpr int ESTRIDE = 84;

__launch_bounds__(256, 2)
__global__ void stair_attn_fb(const float* __restrict__ Qg,
                              const float* __restrict__ Kg,
                              const float* __restrict__ Vg,
                              const float* __restrict__ PEg,
                              float* __restrict__ Og) {
  __shared__ __align__(16) unsigned short Kb[64 * 64];
  __shared__ __align__(16) unsigned short Vt[64 * 64];
  __shared__ __align__(16) unsigned short Pb[128 * 64];
  __shared__ __align__(16) float Elds[4 * 16 * ESTRIDE];
  __shared__ __align__(16) unsigned short Plds[4 * 16 * 64];

  const int tid = threadIdx.x;
  const int w = tid >> 6;
  const int lane = tid & 63;
  const int g = lane >> 4;
  const int q15 = lane & 15;

  const int bid = blockIdx.x;
  const int bh = bid & 15;
  const int jid = bid >> 4;
  const int mt = (jid < 16) ? (2 * jid) : (63 - 2 * jid);
  const int m0 = mt * 64;

  const float* Qb = Qg + (size_t)bh * Mn * Dn;
  const float* Kbase = Kg + (size_t)bh * Mn * Dn;
  const float* Vbase = Vg + (size_t)bh * Mn * Dn;
  float* Ob = Og + (size_t)bh * Mn * Dn;

  short8 aq[2];
  {
    const float* qp = Qb + (size_t)(m0 + 16 * w + q15) * Dn;
#pragma unroll
    for (int s = 0; s < 2; ++s) {
      const float4* p = (const float4*)(qp + s * 32 + g * 8);
      float4 f0 = p[0], f1 = p[1];
      short8 a;
      a[0]=(short)bfbits(f0.x); a[1]=(short)bfbits(f0.y); a[2]=(short)bfbits(f0.z); a[3]=(short)bfbits(f0.w);
      a[4]=(short)bfbits(f1.x); a[5]=(short)bfbits(f1.y); a[6]=(short)bfbits(f1.z); a[7]=(short)bfbits(f1.w);
      aq[s] = a;
    }
  }

  float mrun[4], lrun[4];
  f32x4 o[4] = {};
#pragma unroll
  for (int r = 0; r < 4; ++r) { mrun[r] = -1e30f; lrun[r] = 0.0f; }

  const int ntiles = mt + 1;
  const int dso = g * 8;

  for (int t = 0; t < ntiles; ++t) {
    const int l0 = t * 64;
    __syncthreads();
    {
      const int l = tid >> 2;
      const int dq = (tid & 3) * 16;
      const float* kp = Kbase + (size_t)(l0 + l) * Dn + dq;
      short8 u0, u1;
      {
        float4 f = ((const float4*)kp)[0];
        u0[0]=(short)bfbits(f.x); u0[1]=(short)bfbits(f.y); u0[2]=(short)bfbits(f.z); u0[3]=(short)bfbits(f.w);
        f = ((const float4*)kp)[1];
        u0[4]=(short)bfbits(f.x); u0[5]=(short)bfbits(f.y); u0[6]=(short)bfbits(f.z); u0[7]=(short)bfbits(f.w);
        f = ((const float4*)kp)[2];
        u1[0]=(short)bfbits(f.x); u1[1]=(short)bfbits(f.y); u1[2]=(short)bfbits(f.z); u1[3]=(short)bfbits(f.w);
        f = ((const float4*)kp)[3];
        u1[4]=(short)bfbits(f.x); u1[5]=(short)bfbits(f.y); u1[6]=(short)bfbits(f.z); u1[7]=(short)bfbits(f.w);
      }
      const int swz = (l & 7) << 3;
      *(short8*)&Kb[(l * 64 + dq) ^ swz] = u0;
      *(short8*)&Kb[(l * 64 + dq + 8) ^ swz] = u1;
    }
    {
      const int lrow = lane;
      const int ds = w * 16;
      const float* vp = Vbase + (size_t)(l0 + lrow) * Dn + ds;
#pragma unroll
      for (int i = 0; i < 4; ++i) {
        float4 f = ((const float4*)vp)[i];
        int c0 = ds + 4 * i;
        Vt[((c0 + 0) * 64 + lrow) ^ (((c0 + 0) & 7) << 3)] = bfbits(f.x);
        Vt[((c0 + 1) * 64 + lrow) ^ (((c0 + 1) & 7) << 3)] = bfbits(f.y);
        Vt[((c0 + 2) * 64 + lrow) ^ (((c0 + 2) & 7) << 3)] = bfbits(f.z);
        Vt[((c0 + 3) * 64 + lrow) ^ (((c0 + 3) & 7) << 3)] = bfbits(f.w);
      }
    }
    {
      const int d = lane;
      const int cc = w * 32;
      const int cb = (2048 - 64) - m0 + l0;
      const float* pp = PEg + (size_t)d * LIMn + (cb + cc);
      if (cb + cc + 31 < LIMn) {
#pragma unroll
        for (int i = 0; i < 8; ++i) {
          float4 f = ((const float4*)pp)[i];
          int c0 = cc + 4 * i;
          Pb[((c0 + 0) * 64 + d) ^ (((c0 + 0) & 7) << 3)] = bfbits(f.x);
          Pb[((c0 + 1) * 64 + d) ^ (((c0 + 1) & 7) << 3)] = bfbits(f.y);
          Pb[((c0 + 2) * 64 + d) ^ (((c0 + 2) & 7) << 3)] = bfbits(f.z);
          Pb[((c0 + 3) * 64 + d) ^ (((c0 + 3) & 7) << 3)] = bfbits(f.w);
        }
      } else {
        for (int i = 0; i < 32; ++i) {
          int cabs = cb + cc + i;
          float f = (cabs < LIMn) ? pp[i] : 0.0f;
          int c0 = cc + i;
          Pb[(c0 * 64 + d) ^ ((c0 & 7) << 3)] = bfbits(f);
        }
      }
    }
    __syncthreads();

    f32x4 qk[4] = {};
#pragma unroll
    for (int s = 0; s < 2; ++s)
#pragma unroll
      for (int nt = 0; nt < 4; ++nt) {
        int l = nt * 16 + q15;
        short8 b = *(short8*)&Kb[(l * 64 + s * 32 + dso) ^ ((l & 7) << 3)];
        qk[nt] = MFMA16(aq[s], b, qk[nt]);
      }

    f32x4 ev[5] = {};
    const int ntb = 3 - w;
#pragma unroll
    for (int s = 0; s < 2; ++s)
#pragma unroll
      for (int u5 = 0; u5 < 5; ++u5) {
        int c = (ntb + u5) * 16 + q15;
        short8 b = *(short8*)&Pb[(c * 64 + s * 32 + dso) ^ ((c & 7) << 3)];
        ev[u5] = MFMA16(aq[s], b, ev[u5]);
      }
    float* Ew = Elds + w * 16 * ESTRIDE;
#pragma unroll
    for (int u5 = 0; u5 < 5; ++u5)
#pragma unroll
      for (int r = 0; r < 4; ++r)
        Ew[(g * 4 + r) * ESTRIDE + u5 * 16 + q15] = ev[u5][r];

    const bool diag = (t == ntiles - 1);
    float sv[4][4];
#pragma unroll
    for (int nt = 0; nt < 4; ++nt) {
      int li = nt * 16 + q15;
#pragma unroll
      for (int r = 0; r < 4; ++r) {
        int rw = g * 4 + r;
        float eread = Ew[rw * ESTRIDE + (15 - rw + li)];
        bool masked = diag && (li > (16 * w + rw));
        sv[nt][r] = masked ? -1e30f : (qk[nt][r] + eread) * 0.125f;
      }
    }

    float mnew[4], alpha[4];
#pragma unroll
    for (int r = 0; r < 4; ++r) {
      float mx = fmaxf(fmaxf(sv[0][r], sv[1][r]), fmaxf(sv[2][r], sv[3][r]));
      mx = fmaxf(mx, __shfl_xor(mx, 1));
      mx = fmaxf(mx, __shfl_xor(mx, 2));
      mx = fmaxf(mx, __shfl_xor(mx, 4));
      mx = fmaxf(mx, __shfl_xor(mx, 8));
      float mn = fmaxf(mrun[r], mx);
      alpha[r] = exp2f((mrun[r] - mn) * 1.44269504f);
      mnew[r] = mn;
      mrun[r] = mn;
    }
    float pexp[4][4];
#pragma unroll
    for (int nt = 0; nt < 4; ++nt)
#pragma unroll
      for (int r = 0; r < 4; ++r)
        pexp[nt][r] = exp2f((sv[nt][r] - mnew[r]) * 1.44269504f);
#pragma unroll
    for (int r = 0; r < 4; ++r) {
      float sum = (pexp[0][r] + pexp[1][r]) + (pexp[2][r] + pexp[3][r]);
      sum += __shfl_xor(sum, 1);
      sum += __shfl_xor(sum, 2);
      sum += __shfl_xor(sum, 4);
      sum += __shfl_xor(sum, 8);
      lrun[r] = lrun[r] * alpha[r] + sum;
      o[0][r] *= alpha[r];
      o[1][r] *= alpha[r];
      o[2][r] *= alpha[r];
      o[3][r] *= alpha[r];
    }

    unsigned short* Pw = Plds + w * 16 * 64;
#pragma unroll
    for (int nt = 0; nt < 4; ++nt)
#pragma unroll
      for (int r = 0; r < 4; ++r) {
        int rw = g * 4 + r;
        Pw[(rw * 64 + nt * 16 + q15) ^ ((rw & 7) << 3)] = bfbits(pexp[nt][r]);
      }
    short8 pa[2];
#pragma unroll
    for (int s = 0; s < 2; ++s)
      pa[s] = *(short8*)&Pw[(q15 * 64 + s * 32 + dso) ^ ((q15 & 7) << 3)];

#pragma unroll
    for (int s = 0; s < 2; ++s)
#pragma unroll
      for (int nt = 0; nt < 4; ++nt) {
        int d = nt * 16 + q15;
        short8 b = *(short8*)&Vt[(d * 64 + s * 32 + dso) ^ ((d & 7) << 3)];
        o[nt] = MFMA16(pa[s], b, o[nt]);
      }
  }

#pragma unroll
  for (int nt = 0; nt < 4; ++nt)
#pragma unroll
    for (int r = 0; r < 4; ++r) {
      int m = m0 + 16 * w + g * 4 + r;
      Ob[(size_t)m * Dn + nt * 16 + q15] = o[nt][r] / lrun[r];
    }
}

// ---------------- launch ----------------

extern "C" void kernel_launch(void* const* d_in, const int* in_sizes, int n_in,
                              void* d_out, int out_size, void* d_ws, size_t ws_size,
                              hipStream_t stream) {
  (void)in_sizes; (void)n_in; (void)out_size;
  const float* Q  = (const float*)d_in[0];
  const float* K  = (const float*)d_in[1];
  const float* V  = (const float*)d_in[2];
  const float* PE = (const float*)d_in[3];
  float* Out = (float*)d_out;

  const size_t szK = (size_t)BH * Mn * Dn * sizeof(unsigned short);  // 4 MB
  const size_t szV = szK;                                            // 4 MB
  const size_t szP = (size_t)PEROWS * Dn * sizeof(unsigned short);   // 264 KB
  const size_t need = szK + szV + szP;

  if (ws_size >= need) {
    unsigned short* Kbf = (unsigned short*)d_ws;
    unsigned short* Vt  = (unsigned short*)((char*)d_ws + szK);
    unsigned short* PEt = (unsigned short*)((char*)d_ws + szK + szV);

    hipLaunchKernelGGL(prep_k,   dim3(BH * Mn * Dn / (256 * 8)), dim3(256), 0, stream, K, Kbf);
    hipLaunchKernelGGL(prep_vt,  dim3(BH * (Mn / 64)), dim3(256), 0, stream, V, Vt);
    hipLaunchKernelGGL(prep_pet, dim3(PEROWS / 64), dim3(256), 0, stream, PE, PEt);
    hipLaunchKernelGGL(stair_attn_main, dim3(BH * (Mn / 64) * 4), dim3(64), 0, stream,
                       Q, Kbf, Vt, PEt, Out);
  } else {
    hipLaunchKernelGGL(stair_attn_fb, dim3(512), dim3(256), 0, stream, Q, K, V, PE, Out);
  }
}

// Round 3
// 89.840 us; speedup vs baseline: 2.3524x; 2.3524x over previous
//
#include <hip/hip_runtime.h>
#include <hip/hip_bf16.h>

typedef __attribute__((ext_vector_type(8))) short short8;
typedef __attribute__((ext_vector_type(4))) float f32x4;

#define MFMA16(A, B, C) __builtin_amdgcn_mfma_f32_16x16x32_bf16((A), (B), (C), 0, 0, 0)

#define GL16(gp, lp) __builtin_amdgcn_global_load_lds( \
    (const __attribute__((address_space(1))) void*)(gp), \
    (__attribute__((address_space(3))) void*)(lp), 16, 0, 0)

__device__ __forceinline__ unsigned short bfbits(float f) {
  return __builtin_bit_cast(unsigned short, (__bf16)f);
}

constexpr int BH = 16;
constexpr int Mn = 2048;
constexpr int Dn = 64;
constexpr int LIMn = 2048;
// fragment sizes (in unsigned shorts)
constexpr size_t KF_SHORTS = (size_t)BH * 32 * 8 * 512;  // 16 heads * 32 ltiles * 8 frags * 1KB
constexpr size_t PE_JROWS = 132;                          // 2112 cols / 16
constexpr size_t PEF_SHORTS = PE_JROWS * 2 * 512;

// ---------------- fused prep: fp32 -> bf16 MFMA-fragment-tiled layouts ----------------
// Kf frag (bh,lt,f=nt*2+s): val[lane][j] = K[bh][lt*64+nt*16+(lane&15)][s*32+(lane>>4)*8+j]
// Vf frag:                  val[lane][j] = V[bh][lt*64+s*32+(lane>>4)*8+j][nt*16+(lane&15)]
// PEf frag (jrow,s):        val[lane][j] = PE[s*32+(lane>>4)*8+j][jrow*16+(lane&15)], 0 if col>=2048

__global__ void prep_all(const float* __restrict__ K, const float* __restrict__ V,
                         const float* __restrict__ PE,
                         unsigned short* __restrict__ Kf, unsigned short* __restrict__ Vf,
                         unsigned short* __restrict__ PEf) {
  __shared__ float tA[64 * 64];
  __shared__ float tB[64 * 64];
  const int b = blockIdx.x, tid = threadIdx.x;
  const int w = tid >> 6, lane = tid & 63, g = lane >> 4, q15 = lane & 15;

  if (b < 512) {
    const int bh = b >> 5, lt = b & 31;
    const float* Ks = K + ((size_t)bh * Mn + lt * 64) * Dn;
    const float* Vs = V + ((size_t)bh * Mn + lt * 64) * Dn;
    const int row = tid >> 2, c0 = (tid & 3) * 16;
#pragma unroll
    for (int i = 0; i < 4; ++i) {
      *(float4*)&tA[row * 64 + c0 + 4 * i] = ((const float4*)(Ks + (size_t)row * 64 + c0))[i];
      *(float4*)&tB[row * 64 + c0 + 4 * i] = ((const float4*)(Vs + (size_t)row * 64 + c0))[i];
    }
    __syncthreads();
#pragma unroll
    for (int i = 0; i < 2; ++i) {
      const int f = 2 * w + i, nt = f >> 1, s = f & 1;
      short8 uk, uv;
#pragma unroll
      for (int j = 0; j < 8; ++j) {
        uk[j] = (short)bfbits(tA[(nt * 16 + q15) * 64 + s * 32 + g * 8 + j]);
        uv[j] = (short)bfbits(tB[(s * 32 + g * 8 + j) * 64 + nt * 16 + q15]);
      }
      const size_t base = ((size_t)(bh * 32 + lt) * 8 + f) * 512 + lane * 8;
      *(short8*)&Kf[base] = uk;
      *(short8*)&Vf[base] = uv;
    }
  } else {
    const int pb = b - 512;
    const int c0 = pb * 64;
    const int d = tid >> 2, cc = (tid & 3) * 16;
#pragma unroll
    for (int i = 0; i < 16; ++i) {
      const int c = c0 + cc + i;
      tA[(cc + i) * 64 + d] = (c < LIMn) ? PE[(size_t)d * LIMn + c] : 0.0f;
    }
    __syncthreads();
#pragma unroll
    for (int s = 0; s < 2; ++s) {
      short8 u;
#pragma unroll
      for (int j = 0; j < 8; ++j)
        u[j] = (short)bfbits(tA[(w * 16 + q15) * 64 + s * 32 + g * 8 + j]);
      *(short8*)&PEf[((size_t)(4 * pb + w) * 2 + s) * 512 + lane * 8] = u;
    }
  }
}

// ---------------- main: 4-wave blocks, gload_lds double-buffered K/V, direct-reg PE ----------------

__launch_bounds__(256, 2)
__global__ void stair_main(const float* __restrict__ Qg,
                           const unsigned short* __restrict__ Kf,
                           const unsigned short* __restrict__ Vf,
                           const unsigned short* __restrict__ PEf,
                           float* __restrict__ Og) {
  __shared__ __align__(16) unsigned short Kbuf[2][4096];   // 8 frags * 1KB, dbuf
  __shared__ __align__(16) unsigned short Vbuf[2][4096];
  __shared__ __align__(16) unsigned short Plds[4][1024];   // per-wave P bounce

  const int tid = threadIdx.x;
  const int w = tid >> 6, lane = tid & 63, g = lane >> 4, q15 = lane & 15;

  const int bid = blockIdx.x;
  const int bh = bid & 15;          // head -> fixed XCD (bid%8 == bh%8): K/V L2-resident
  const int mt = 31 - (bid >> 4);   // heavy blocks first
  const int m0w = mt * 64 + w * 16;

  const float* Qb = Qg + (size_t)bh * Mn * Dn;
  float* Ob = Og + (size_t)bh * Mn * Dn;

  // Q A-fragments (row=lane&15, k=(lane>>4)*8+j, +32 per s)
  short8 aq[2];
  {
    const float* qp = Qb + (size_t)(m0w + q15) * Dn;
#pragma unroll
    for (int s = 0; s < 2; ++s) {
      const float4* p = (const float4*)(qp + s * 32 + g * 8);
      float4 f0 = p[0], f1 = p[1];
      short8 a;
      a[0]=(short)bfbits(f0.x); a[1]=(short)bfbits(f0.y); a[2]=(short)bfbits(f0.z); a[3]=(short)bfbits(f0.w);
      a[4]=(short)bfbits(f1.x); a[5]=(short)bfbits(f1.y); a[6]=(short)bfbits(f1.z); a[7]=(short)bfbits(f1.w);
      aq[s] = a;
    }
  }

  float mrun[4], lrun[4];
  f32x4 o[4] = {};
#pragma unroll
  for (int r = 0; r < 4; ++r) { mrun[r] = -1e30f; lrun[r] = 0.0f; }

  // stage tile t's K/V frags into buffer b (4 gload_lds per wave, 1KB each)
  auto STAGE = [&](int b, int t) {
    const size_t toff = ((size_t)(bh * 32 + t) * 8) * 512;
#pragma unroll
    for (int i = 0; i < 2; ++i) {
      const int f = 2 * w + i;
      const size_t off = toff + (size_t)f * 512 + lane * 8;
      GL16(&Kf[off], &Kbuf[b][f * 512]);
      GL16(&Vf[off], &Vbuf[b][f * 512]);
    }
  };

  auto BODY = [&](int t, int cur, bool diag) {
    const int ntmax = diag ? w : 3;
    const int u5 = diag ? (w + 2) : 5;   // w<=3 -> w+2<=5
    const int smax = diag ? (w >> 1) : 1;
    const int jbase = 127 - 4 * mt - w + 4 * t;   // PE fragment row-group base

    // QK^T from LDS
    f32x4 qk[4] = {};
#pragma unroll
    for (int s = 0; s < 2; ++s)
#pragma unroll
      for (int nt = 0; nt < 4; ++nt)
        if (nt <= ntmax) {
          short8 bfr = *(const short8*)&Kbuf[cur][(nt * 2 + s) * 512 + lane * 8];
          qk[nt] = MFMA16(aq[s], bfr, qk[nt]);
        }

    // E band, PE fragments direct from global (L2-hot)
    f32x4 ev[5] = {};
#pragma unroll
    for (int s = 0; s < 2; ++s)
#pragma unroll
      for (int u = 0; u < 5; ++u)
        if (u < u5) {
          short8 bfr = *(const short8*)&PEf[((size_t)(jbase + u) * 2 + s) * 512 + lane * 8];
          ev[u] = MFMA16(aq[s], bfr, ev[u]);
        }

    // diagonal gather via lane rotate (verified r2): E[rw][15-rw+li]
    float sv[4][4];
#pragma unroll
    for (int nt = 0; nt < 4; ++nt)
#pragma unroll
      for (int r = 0; r < 4; ++r) sv[nt][r] = -1e30f;
#pragma unroll
    for (int nt = 0; nt < 4; ++nt)
      if (nt <= ntmax) {
#pragma unroll
        for (int r = 0; r < 4; ++r) {
          const int rw = g * 4 + r;
          const int srcLane = (lane & 48) | ((q15 + 15 - rw) & 15);
          float e_lo = __shfl(ev[nt][r], srcLane, 64);
          float e_hi = __shfl(ev[nt + 1][r], srcLane, 64);
          float er = (q15 > rw) ? e_hi : e_lo;
          const int li = nt * 16 + q15;
          bool masked = diag && (li > w * 16 + rw);
          sv[nt][r] = masked ? -1e30f : (qk[nt][r] + er) * 0.125f;
        }
      }

    // online softmax
    float mnew[4], alpha[4];
#pragma unroll
    for (int r = 0; r < 4; ++r) {
      float mx = fmaxf(fmaxf(sv[0][r], sv[1][r]), fmaxf(sv[2][r], sv[3][r]));
      mx = fmaxf(mx, __shfl_xor(mx, 1));
      mx = fmaxf(mx, __shfl_xor(mx, 2));
      mx = fmaxf(mx, __shfl_xor(mx, 4));
      mx = fmaxf(mx, __shfl_xor(mx, 8));
      float mn = fmaxf(mrun[r], mx);
      alpha[r] = exp2f((mrun[r] - mn) * 1.44269504f);
      mnew[r] = mn;
      mrun[r] = mn;
    }
    float pexp[4][4];
#pragma unroll
    for (int nt = 0; nt < 4; ++nt)
#pragma unroll
      for (int r = 0; r < 4; ++r)
        pexp[nt][r] = exp2f((sv[nt][r] - mnew[r]) * 1.44269504f);
#pragma unroll
    for (int r = 0; r < 4; ++r) {
      float sum = (pexp[0][r] + pexp[1][r]) + (pexp[2][r] + pexp[3][r]);
      sum += __shfl_xor(sum, 1);
      sum += __shfl_xor(sum, 2);
      sum += __shfl_xor(sum, 4);
      sum += __shfl_xor(sum, 8);
      lrun[r] = lrun[r] * alpha[r] + sum;
      o[0][r] *= alpha[r];
      o[1][r] *= alpha[r];
      o[2][r] *= alpha[r];
      o[3][r] *= alpha[r];
    }

    // P -> per-wave LDS bounce -> A-frag (no barrier: same wave)
#pragma unroll
    for (int nt = 0; nt < 4; ++nt)
#pragma unroll
      for (int r = 0; r < 4; ++r) {
        const int rw = g * 4 + r;
        Plds[w][(rw * 64 + nt * 16 + q15) ^ ((rw & 7) << 3)] = bfbits(pexp[nt][r]);
      }
    short8 pa[2];
#pragma unroll
    for (int s = 0; s < 2; ++s)
      if (s <= smax)
        pa[s] = *(short8*)&Plds[w][(q15 * 64 + s * 32 + g * 8) ^ ((q15 & 7) << 3)];

    // PV from LDS
#pragma unroll
    for (int s = 0; s < 2; ++s)
      if (s <= smax)
#pragma unroll
        for (int nt = 0; nt < 4; ++nt) {
          short8 bfr = *(const short8*)&Vbuf[cur][(nt * 2 + s) * 512 + lane * 8];
          o[nt] = MFMA16(pa[s], bfr, o[nt]);
        }
  };

  STAGE(0, 0);
  __syncthreads();
  int cur = 0;
  for (int t = 0; t < mt; ++t) {
    STAGE(cur ^ 1, t + 1);       // prefetch in flight across whole compute phase
    BODY(t, cur, false);
    __syncthreads();             // drains vmcnt -> next buffer ready
    cur ^= 1;
  }
  BODY(mt, cur, true);

  // epilogue
#pragma unroll
  for (int nt = 0; nt < 4; ++nt)
#pragma unroll
    for (int r = 0; r < 4; ++r) {
      const int m = m0w + g * 4 + r;
      Ob[(size_t)m * Dn + nt * 16 + q15] = o[nt][r] / lrun[r];
    }
}

// ---------------- fallback (round-1 kernel, passed @118us) ----------------

constexpr int ESTRIDE = 84;

__launch_bounds__(256, 2)
__global__ void stair_attn_fb(const float* __restrict__ Qg,
                              const float* __restrict__ Kg,
                              const float* __restrict__ Vg,
                              const float* __restrict__ PEg,
                              float* __restrict__ Og) {
  __shared__ __align__(16) unsigned short Kb[64 * 64];
  __shared__ __align__(16) unsigned short Vt[64 * 64];
  __shared__ __align__(16) unsigned short Pb[128 * 64];
  __shared__ __align__(16) float Elds[4 * 16 * ESTRIDE];
  __shared__ __align__(16) unsigned short Plds[4 * 16 * 64];

  const int tid = threadIdx.x;
  const int w = tid >> 6;
  const int lane = tid & 63;
  const int g = lane >> 4;
  const int q15 = lane & 15;

  const int bid = blockIdx.x;
  const int bh = bid & 15;
  const int jid = bid >> 4;
  const int mt = (jid < 16) ? (2 * jid) : (63 - 2 * jid);
  const int m0 = mt * 64;

  const float* Qb = Qg + (size_t)bh * Mn * Dn;
  const float* Kbase = Kg + (size_t)bh * Mn * Dn;
  const float* Vbase = Vg + (size_t)bh * Mn * Dn;
  float* Ob = Og + (size_t)bh * Mn * Dn;

  short8 aq[2];
  {
    const float* qp = Qb + (size_t)(m0 + 16 * w + q15) * Dn;
#pragma unroll
    for (int s = 0; s < 2; ++s) {
      const float4* p = (const float4*)(qp + s * 32 + g * 8);
      float4 f0 = p[0], f1 = p[1];
      short8 a;
      a[0]=(short)bfbits(f0.x); a[1]=(short)bfbits(f0.y); a[2]=(short)bfbits(f0.z); a[3]=(short)bfbits(f0.w);
      a[4]=(short)bfbits(f1.x); a[5]=(short)bfbits(f1.y); a[6]=(short)bfbits(f1.z); a[7]=(short)bfbits(f1.w);
      aq[s] = a;
    }
  }

  float mrun[4], lrun[4];
  f32x4 o[4] = {};
#pragma unroll
  for (int r = 0; r < 4; ++r) { mrun[r] = -1e30f; lrun[r] = 0.0f; }

  const int ntiles = mt + 1;
  const int dso = g * 8;

  for (int t = 0; t < ntiles; ++t) {
    const int l0 = t * 64;
    __syncthreads();
    {
      const int l = tid >> 2;
      const int dq = (tid & 3) * 16;
      const float* kp = Kbase + (size_t)(l0 + l) * Dn + dq;
      short8 u0, u1;
      {
        float4 f = ((const float4*)kp)[0];
        u0[0]=(short)bfbits(f.x); u0[1]=(short)bfbits(f.y); u0[2]=(short)bfbits(f.z); u0[3]=(short)bfbits(f.w);
        f = ((const float4*)kp)[1];
        u0[4]=(short)bfbits(f.x); u0[5]=(short)bfbits(f.y); u0[6]=(short)bfbits(f.z); u0[7]=(short)bfbits(f.w);
        f = ((const float4*)kp)[2];
        u1[0]=(short)bfbits(f.x); u1[1]=(short)bfbits(f.y); u1[2]=(short)bfbits(f.z); u1[3]=(short)bfbits(f.w);
        f = ((const float4*)kp)[3];
        u1[4]=(short)bfbits(f.x); u1[5]=(short)bfbits(f.y); u1[6]=(short)bfbits(f.z); u1[7]=(short)bfbits(f.w);
      }
      const int swz = (l & 7) << 3;
      *(short8*)&Kb[(l * 64 + dq) ^ swz] = u0;
      *(short8*)&Kb[(l * 64 + dq + 8) ^ swz] = u1;
    }
    {
      const int lrow = lane;
      const int ds = w * 16;
      const float* vp = Vbase + (size_t)(l0 + lrow) * Dn + ds;
#pragma unroll
      for (int i = 0; i < 4; ++i) {
        float4 f = ((const float4*)vp)[i];
        int c0 = ds + 4 * i;
        Vt[((c0 + 0) * 64 + lrow) ^ (((c0 + 0) & 7) << 3)] = bfbits(f.x);
        Vt[((c0 + 1) * 64 + lrow) ^ (((c0 + 1) & 7) << 3)] = bfbits(f.y);
        Vt[((c0 + 2) * 64 + lrow) ^ (((c0 + 2) & 7) << 3)] = bfbits(f.z);
        Vt[((c0 + 3) * 64 + lrow) ^ (((c0 + 3) & 7) << 3)] = bfbits(f.w);
      }
    }
    {
      const int d = lane;
      const int cc = w * 32;
      const int cb = (2048 - 64) - m0 + l0;
      const float* pp = PEg + (size_t)d * LIMn + (cb + cc);
      if (cb + cc + 31 < LIMn) {
#pragma unroll
        for (int i = 0; i < 8; ++i) {
          float4 f = ((const float4*)pp)[i];
          int c0 = cc + 4 * i;
          Pb[((c0 + 0) * 64 + d) ^ (((c0 + 0) & 7) << 3)] = bfbits(f.x);
          Pb[((c0 + 1) * 64 + d) ^ (((c0 + 1) & 7) << 3)] = bfbits(f.y);
          Pb[((c0 + 2) * 64 + d) ^ (((c0 + 2) & 7) << 3)] = bfbits(f.z);
          Pb[((c0 + 3) * 64 + d) ^ (((c0 + 3) & 7) << 3)] = bfbits(f.w);
        }
      } else {
        for (int i = 0; i < 32; ++i) {
          int cabs = cb + cc + i;
          float f = (cabs < LIMn) ? pp[i] : 0.0f;
          int c0 = cc + i;
          Pb[(c0 * 64 + d) ^ ((c0 & 7) << 3)] = bfbits(f);
        }
      }
    }
    __syncthreads();

    f32x4 qk[4] = {};
#pragma unroll
    for (int s = 0; s < 2; ++s)
#pragma unroll
      for (int nt = 0; nt < 4; ++nt) {
        int l = nt * 16 + q15;
        short8 b = *(short8*)&Kb[(l * 64 + s * 32 + dso) ^ ((l & 7) << 3)];
        qk[nt] = MFMA16(aq[s], b, qk[nt]);
      }

    f32x4 ev[5] = {};
    const int ntb = 3 - w;
#pragma unroll
    for (int s = 0; s < 2; ++s)
#pragma unroll
      for (int u5 = 0; u5 < 5; ++u5) {
        int c = (ntb + u5) * 16 + q15;
        short8 b = *(short8*)&Pb[(c * 64 + s * 32 + dso) ^ ((c & 7) << 3)];
        ev[u5] = MFMA16(aq[s], b, ev[u5]);
      }
    float* Ew = Elds + w * 16 * ESTRIDE;
#pragma unroll
    for (int u5 = 0; u5 < 5; ++u5)
#pragma unroll
      for (int r = 0; r < 4; ++r)
        Ew[(g * 4 + r) * ESTRIDE + u5 * 16 + q15] = ev[u5][r];

    const bool diag = (t == ntiles - 1);
    float sv[4][4];
#pragma unroll
    for (int nt = 0; nt < 4; ++nt) {
      int li = nt * 16 + q15;
#pragma unroll
      for (int r = 0; r < 4; ++r) {
        int rw = g * 4 + r;
        float eread = Ew[rw * ESTRIDE + (15 - rw + li)];
        bool masked = diag && (li > (16 * w + rw));
        sv[nt][r] = masked ? -1e30f : (qk[nt][r] + eread) * 0.125f;
      }
    }

    float mnew[4], alpha[4];
#pragma unroll
    for (int r = 0; r < 4; ++r) {
      float mx = fmaxf(fmaxf(sv[0][r], sv[1][r]), fmaxf(sv[2][r], sv[3][r]));
      mx = fmaxf(mx, __shfl_xor(mx, 1));
      mx = fmaxf(mx, __shfl_xor(mx, 2));
      mx = fmaxf(mx, __shfl_xor(mx, 4));
      mx = fmaxf(mx, __shfl_xor(mx, 8));
      float mn = fmaxf(mrun[r], mx);
      alpha[r] = exp2f((mrun[r] - mn) * 1.44269504f);
      mnew[r] = mn;
      mrun[r] = mn;
    }
    float pexp[4][4];
#pragma unroll
    for (int nt = 0; nt < 4; ++nt)
#pragma unroll
      for (int r = 0; r < 4; ++r)
        pexp[nt][r] = exp2f((sv[nt][r] - mnew[r]) * 1.44269504f);
#pragma unroll
    for (int r = 0; r < 4; ++r) {
      float sum = (pexp[0][r] + pexp[1][r]) + (pexp[2][r] + pexp[3][r]);
      sum += __shfl_xor(sum, 1);
      sum += __shfl_xor(sum, 2);
      sum += __shfl_xor(sum, 4);
      sum += __shfl_xor(sum, 8);
      lrun[r] = lrun[r] * alpha[r] + sum;
      o[0][r] *= alpha[r];
      o[1][r] *= alpha[r];
      o[2][r] *= alpha[r];
      o[3][r] *= alpha[r];
    }

    unsigned short* Pw = Plds + w * 16 * 64;
#pragma unroll
    for (int nt = 0; nt < 4; ++nt)
#pragma unroll
      for (int r = 0; r < 4; ++r) {
        int rw = g * 4 + r;
        Pw[(rw * 64 + nt * 16 + q15) ^ ((rw & 7) << 3)] = bfbits(pexp[nt][r]);
      }
    short8 pa[2];
#pragma unroll
    for (int s = 0; s < 2; ++s)
      pa[s] = *(short8*)&Pw[(q15 * 64 + s * 32 + dso) ^ ((q15 & 7) << 3)];

#pragma unroll
    for (int s = 0; s < 2; ++s)
#pragma unroll
      for (int nt = 0; nt < 4; ++nt) {
        int d = nt * 16 + q15;
        short8 b = *(short8*)&Vt[(d * 64 + s * 32 + dso) ^ ((d & 7) << 3)];
        o[nt] = MFMA16(pa[s], b, o[nt]);
      }
  }

#pragma unroll
  for (int nt = 0; nt < 4; ++nt)
#pragma unroll
    for (int r = 0; r < 4; ++r) {
      int m = m0 + 16 * w + g * 4 + r;
      Ob[(size_t)m * Dn + nt * 16 + q15] = o[nt][r] / lrun[r];
    }
}

// ---------------- launch ----------------

extern "C" void kernel_launch(void* const* d_in, const int* in_sizes, int n_in,
                              void* d_out, int out_size, void* d_ws, size_t ws_size,
                              hipStream_t stream) {
  (void)in_sizes; (void)n_in; (void)out_size;
  const float* Q  = (const float*)d_in[0];
  const float* K  = (const float*)d_in[1];
  const float* V  = (const float*)d_in[2];
  const float* PE = (const float*)d_in[3];
  float* Out = (float*)d_out;

  const size_t szK = KF_SHORTS * sizeof(unsigned short);   // 4 MB
  const size_t szV = szK;                                   // 4 MB
  const size_t szP = PEF_SHORTS * sizeof(unsigned short);   // 264 KB
  const size_t need = szK + szV + szP;

  if (ws_size >= need) {
    unsigned short* Kf  = (unsigned short*)d_ws;
    unsigned short* Vf  = (unsigned short*)((char*)d_ws + szK);
    unsigned short* PEf = (unsigned short*)((char*)d_ws + szK + szV);

    hipLaunchKernelGGL(prep_all, dim3(512 + 33), dim3(256), 0, stream, K, V, PE, Kf, Vf, PEf);
    hipLaunchKernelGGL(stair_main, dim3(512), dim3(256), 0, stream, Q, Kf, Vf, PEf, Out);
  } else {
    hipLaunchKernelGGL(stair_attn_fb, dim3(512), dim3(256), 0, stream, Q, K, V, PE, Out);
  }
}

// Round 4
// 88.166 us; speedup vs baseline: 2.3971x; 1.0190x over previous
//
#include <hip/hip_runtime.h>
#include <hip/hip_bf16.h>

typedef __attribute__((ext_vector_type(8))) short short8;
typedef __attribute__((ext_vector_type(4))) float f32x4;

#define MFMA16(A, B, C) __builtin_amdgcn_mfma_f32_16x16x32_bf16((A), (B), (C), 0, 0, 0)

#define GL16(gp, lp) __builtin_amdgcn_global_load_lds( \
    (const __attribute__((address_space(1))) void*)(gp), \
    (__attribute__((address_space(3))) void*)(lp), 16, 0, 0)

__device__ __forceinline__ unsigned short bfbits(float f) {
  return __builtin_bit_cast(unsigned short, (__bf16)f);
}

constexpr int BH = 16;
constexpr int Mn = 2048;
constexpr int Dn = 64;
constexpr int LIMn = 2048;
constexpr size_t KF_SHORTS = (size_t)BH * 32 * 8 * 512;
constexpr size_t PE_JROWS = 132;
constexpr size_t PEF_SHORTS = PE_JROWS * 2 * 512;
constexpr int PART_SLOT = 4224;        // 64*64 o + 64 m + 64 l floats
constexpr int SLOTS_PER_HEAD = 72;     // sum of chunks for mt=8..31

__device__ __forceinline__ int part_offs(int mt) {
  return (mt < 16) ? 2 * (mt - 8) : (mt < 24 ? 16 + 3 * (mt - 16) : 40 + 4 * (mt - 24));
}

// ---------------- prep: fp32 -> bf16 MFMA-fragment-tiled layouts (verified r3) ----------------

__global__ void prep_all(const float* __restrict__ K, const float* __restrict__ V,
                         const float* __restrict__ PE,
                         unsigned short* __restrict__ Kf, unsigned short* __restrict__ Vf,
                         unsigned short* __restrict__ PEf) {
  __shared__ float tA[64 * 64];
  __shared__ float tB[64 * 64];
  const int b = blockIdx.x, tid = threadIdx.x;
  const int w = tid >> 6, lane = tid & 63, g = lane >> 4, q15 = lane & 15;

  if (b < 512) {
    const int bh = b >> 5, lt = b & 31;
    const float* Ks = K + ((size_t)bh * Mn + lt * 64) * Dn;
    const float* Vs = V + ((size_t)bh * Mn + lt * 64) * Dn;
    const int row = tid >> 2, c0 = (tid & 3) * 16;
#pragma unroll
    for (int i = 0; i < 4; ++i) {
      *(float4*)&tA[row * 64 + c0 + 4 * i] = ((const float4*)(Ks + (size_t)row * 64 + c0))[i];
      *(float4*)&tB[row * 64 + c0 + 4 * i] = ((const float4*)(Vs + (size_t)row * 64 + c0))[i];
    }
    __syncthreads();
#pragma unroll
    for (int i = 0; i < 2; ++i) {
      const int f = 2 * w + i, nt = f >> 1, s = f & 1;
      short8 uk, uv;
#pragma unroll
      for (int j = 0; j < 8; ++j) {
        uk[j] = (short)bfbits(tA[(nt * 16 + q15) * 64 + s * 32 + g * 8 + j]);
        uv[j] = (short)bfbits(tB[(s * 32 + g * 8 + j) * 64 + nt * 16 + q15]);
      }
      const size_t base = ((size_t)(bh * 32 + lt) * 8 + f) * 512 + lane * 8;
      *(short8*)&Kf[base] = uk;
      *(short8*)&Vf[base] = uv;
    }
  } else {
    const int pb = b - 512;
    const int c0 = pb * 64;
    const int d = tid >> 2, cc = (tid & 3) * 16;
#pragma unroll
    for (int i = 0; i < 16; ++i) {
      const int c = c0 + cc + i;
      tA[(cc + i) * 64 + d] = (c < LIMn) ? PE[(size_t)d * LIMn + c] : 0.0f;
    }
    __syncthreads();
#pragma unroll
    for (int s = 0; s < 2; ++s) {
      short8 u;
#pragma unroll
      for (int j = 0; j < 8; ++j)
        u[j] = (short)bfbits(tA[(w * 16 + q15) * 64 + s * 32 + g * 8 + j]);
      *(short8*)&PEf[((size_t)(4 * pb + w) * 2 + s) * 512 + lane * 8] = u;
    }
  }
}

// ---------------- main: split-K chunks, PE reg-dbuf, defer-max ----------------

__launch_bounds__(256, 2)
__global__ void stair_main(const float* __restrict__ Qg,
                           const unsigned short* __restrict__ Kf,
                           const unsigned short* __restrict__ Vf,
                           const unsigned short* __restrict__ PEf,
                           float* __restrict__ Og,
                           float* __restrict__ Part,
                           int split) {
  __shared__ __align__(16) unsigned short Kbuf[2][4096];
  __shared__ __align__(16) unsigned short Vbuf[2][4096];
  __shared__ __align__(16) unsigned short Plds[4][1024];

  const int tid = threadIdx.x;
  const int w = tid >> 6, lane = tid & 63, g = lane >> 4, q15 = lane & 15;
  const int bid = blockIdx.x;

  int bh, mt, chunk, t0, t1, nch;
  bh = bid & 15;                       // head -> fixed XCD: K/V L2-resident
  if (split) {
    const int u = bid >> 4;            // 0..79, heavy-first
    if (u < 32)      { mt = 31 - (u >> 2); chunk = u & 3; }
    else if (u < 56) { const int v = u - 32, q = v / 3; mt = 23 - q; chunk = v - q * 3; }
    else if (u < 72) { const int v = u - 56; mt = 15 - (v >> 1); chunk = v & 1; }
    else             { mt = 7 - (u - 72); chunk = 0; }
    t0 = chunk * 8;
    t1 = (t0 + 8 < mt + 1) ? (t0 + 8) : (mt + 1);
    nch = (mt + 8) >> 3;
  } else {
    mt = 31 - (bid >> 4); chunk = 0; t0 = 0; t1 = mt + 1; nch = 1;
  }
  const int m0w = mt * 64 + w * 16;

  const float* Qb = Qg + (size_t)bh * Mn * Dn;
  float* Ob = Og + (size_t)bh * Mn * Dn;

  // Q A-fragments
  short8 aq[2];
  {
    const float* qp = Qb + (size_t)(m0w + q15) * Dn;
#pragma unroll
    for (int s = 0; s < 2; ++s) {
      const float4* p = (const float4*)(qp + s * 32 + g * 8);
      float4 f0 = p[0], f1 = p[1];
      short8 a;
      a[0]=(short)bfbits(f0.x); a[1]=(short)bfbits(f0.y); a[2]=(short)bfbits(f0.z); a[3]=(short)bfbits(f0.w);
      a[4]=(short)bfbits(f1.x); a[5]=(short)bfbits(f1.y); a[6]=(short)bfbits(f1.z); a[7]=(short)bfbits(f1.w);
      aq[s] = a;
    }
  }

  float mrun[4], lrun[4];
  f32x4 o[4] = {};
#pragma unroll
  for (int r = 0; r < 4; ++r) { mrun[r] = -1e30f; lrun[r] = 0.0f; }

  auto STAGE = [&](int b, int t) {
    const size_t toff = ((size_t)(bh * 32 + t) * 8) * 512;
#pragma unroll
    for (int i = 0; i < 2; ++i) {
      const int f = 2 * w + i;
      const size_t off = toff + (size_t)f * 512 + lane * 8;
      GL16(&Kf[off], &Kbuf[b][f * 512]);
      GL16(&Vf[off], &Vbuf[b][f * 512]);
    }
  };

  int cur = 0;
  STAGE(0, t0);
  short8 pc[2][5];                      // current tile's PE fragments (regs)
  {
    const int jb = 127 - 4 * mt - w + 4 * t0;
#pragma unroll
    for (int s = 0; s < 2; ++s)
#pragma unroll
      for (int u = 0; u < 5; ++u)
        pc[s][u] = *(const short8*)&PEf[((size_t)(jb + u) * 2 + s) * 512 + lane * 8];
  }
  __syncthreads();

  for (int t = t0; t < t1; ++t) {
    const bool last = (t + 1 >= t1);
    if (!last) STAGE(cur ^ 1, t + 1);
    short8 pn[2][5];
    if (!last) {                        // prefetch next tile's PE while computing
      const int jb = 127 - 4 * mt - w + 4 * (t + 1);
#pragma unroll
      for (int s = 0; s < 2; ++s)
#pragma unroll
        for (int u = 0; u < 5; ++u)
          pn[s][u] = *(const short8*)&PEf[((size_t)(jb + u) * 2 + s) * 512 + lane * 8];
    }

    const bool diag = (t == mt);
    const int ntmax = diag ? w : 3;
    const int u5 = diag ? (w + 2) : 5;
    const int smax = diag ? (w >> 1) : 1;

    // QK^T
    f32x4 qk[4] = {};
#pragma unroll
    for (int s = 0; s < 2; ++s)
#pragma unroll
      for (int nt = 0; nt < 4; ++nt)
        if (nt <= ntmax) {
          short8 bfr = *(const short8*)&Kbuf[cur][(nt * 2 + s) * 512 + lane * 8];
          qk[nt] = MFMA16(aq[s], bfr, qk[nt]);
        }

    // E band from register-resident PE
    f32x4 ev[5] = {};
#pragma unroll
    for (int s = 0; s < 2; ++s)
#pragma unroll
      for (int u = 0; u < 5; ++u)
        if (u < u5) ev[u] = MFMA16(aq[s], pc[s][u], ev[u]);

    // diagonal gather via lane rotate (verified r2/r3)
    float sv[4][4];
#pragma unroll
    for (int nt = 0; nt < 4; ++nt)
#pragma unroll
      for (int r = 0; r < 4; ++r) sv[nt][r] = -1e30f;
#pragma unroll
    for (int nt = 0; nt < 4; ++nt)
      if (nt <= ntmax) {
#pragma unroll
        for (int r = 0; r < 4; ++r) {
          const int rw = g * 4 + r;
          const int srcLane = (lane & 48) | ((q15 + 15 - rw) & 15);
          float e_lo = __shfl(ev[nt][r], srcLane, 64);
          float e_hi = __shfl(ev[nt + 1][r], srcLane, 64);
          float er = (q15 > rw) ? e_hi : e_lo;
          const int li = nt * 16 + q15;
          bool masked = diag && (li > w * 16 + rw);
          sv[nt][r] = masked ? -1e30f : (qk[nt][r] + er) * 0.125f;
        }
      }

    // defer-max online softmax
    float lmax[4];
#pragma unroll
    for (int r = 0; r < 4; ++r)
      lmax[r] = fmaxf(fmaxf(sv[0][r], sv[1][r]), fmaxf(sv[2][r], sv[3][r]));
    const bool fast = __all((lmax[0] <= mrun[0] + 8.f) & (lmax[1] <= mrun[1] + 8.f) &
                            (lmax[2] <= mrun[2] + 8.f) & (lmax[3] <= mrun[3] + 8.f));
    if (!fast) {
#pragma unroll
      for (int r = 0; r < 4; ++r) {
        float mx = lmax[r];
        mx = fmaxf(mx, __shfl_xor(mx, 1));
        mx = fmaxf(mx, __shfl_xor(mx, 2));
        mx = fmaxf(mx, __shfl_xor(mx, 4));
        mx = fmaxf(mx, __shfl_xor(mx, 8));
        const float mn = fmaxf(mrun[r], mx);
        const float alpha = exp2f((mrun[r] - mn) * 1.44269504f);
        mrun[r] = mn;
        lrun[r] *= alpha;
        o[0][r] *= alpha; o[1][r] *= alpha; o[2][r] *= alpha; o[3][r] *= alpha;
      }
    }
#pragma unroll
    for (int nt = 0; nt < 4; ++nt)
#pragma unroll
      for (int r = 0; r < 4; ++r)
        sv[nt][r] = exp2f((sv[nt][r] - mrun[r]) * 1.44269504f);
#pragma unroll
    for (int r = 0; r < 4; ++r) {
      float sum = (sv[0][r] + sv[1][r]) + (sv[2][r] + sv[3][r]);
      sum += __shfl_xor(sum, 1);
      sum += __shfl_xor(sum, 2);
      sum += __shfl_xor(sum, 4);
      sum += __shfl_xor(sum, 8);
      lrun[r] += sum;
    }

    // P -> per-wave LDS bounce -> A-frag (no barrier: same wave)
#pragma unroll
    for (int nt = 0; nt < 4; ++nt)
#pragma unroll
      for (int r = 0; r < 4; ++r) {
        const int rw = g * 4 + r;
        Plds[w][(rw * 64 + nt * 16 + q15) ^ ((rw & 7) << 3)] = bfbits(sv[nt][r]);
      }
    short8 pa[2];
#pragma unroll
    for (int s = 0; s < 2; ++s)
      if (s <= smax)
        pa[s] = *(short8*)&Plds[w][(q15 * 64 + s * 32 + g * 8) ^ ((q15 & 7) << 3)];

    // PV
#pragma unroll
    for (int s = 0; s < 2; ++s)
      if (s <= smax)
#pragma unroll
        for (int nt = 0; nt < 4; ++nt) {
          short8 bfr = *(const short8*)&Vbuf[cur][(nt * 2 + s) * 512 + lane * 8];
          o[nt] = MFMA16(pa[s], bfr, o[nt]);
        }

    if (!last) {
#pragma unroll
      for (int s = 0; s < 2; ++s)
#pragma unroll
        for (int u = 0; u < 5; ++u)
          pc[s][u] = pn[s][u];
      __syncthreads();
    }
    cur ^= 1;
  }

  // epilogue
  if (nch == 1) {
#pragma unroll
    for (int nt = 0; nt < 4; ++nt)
#pragma unroll
      for (int r = 0; r < 4; ++r) {
        const int m = m0w + g * 4 + r;
        Ob[(size_t)m * Dn + nt * 16 + q15] = o[nt][r] / lrun[r];
      }
  } else {
    float* ps = Part + ((size_t)bh * SLOTS_PER_HEAD + part_offs(mt) + chunk) * PART_SLOT;
#pragma unroll
    for (int nt = 0; nt < 4; ++nt)
#pragma unroll
      for (int r = 0; r < 4; ++r)
        ps[(w * 16 + g * 4 + r) * 64 + nt * 16 + q15] = o[nt][r];
#pragma unroll
    for (int r = 0; r < 4; ++r)
      if (q15 == g * 4 + r) {
        ps[4096 + w * 16 + q15] = mrun[r];
        ps[4160 + w * 16 + q15] = lrun[r];
      }
  }
}

// ---------------- combine: merge 2-4 chunk partials per (head, mtile>=8) ----------------

__launch_bounds__(256, 4)
__global__ void combine_parts(const float* __restrict__ Part, float* __restrict__ Og) {
  const int bid = blockIdx.x;
  const int bh = bid & 15;
  const int mt = 8 + (bid >> 4);
  const int nch = (mt + 8) >> 3;
  const float* base = Part + ((size_t)bh * SLOTS_PER_HEAD + part_offs(mt)) * PART_SLOT;
  const int tid = threadIdx.x;
  const int row = tid >> 2;
  const int qc = (tid & 3) * 16;

  float mstar = -1e30f;
#pragma unroll
  for (int c = 0; c < 4; ++c)
    if (c < nch) mstar = fmaxf(mstar, base[c * PART_SLOT + 4096 + row]);
  float lsum = 0.f;
  f32x4 acc0 = {}, acc1 = {}, acc2 = {}, acc3 = {};
#pragma unroll
  for (int c = 0; c < 4; ++c)
    if (c < nch) {
      const float* ps = base + c * PART_SLOT;
      const float sc = exp2f((ps[4096 + row] - mstar) * 1.44269504f);
      lsum += ps[4160 + row] * sc;
      const f32x4* op = (const f32x4*)&ps[row * 64 + qc];
      acc0 += op[0] * sc; acc1 += op[1] * sc; acc2 += op[2] * sc; acc3 += op[3] * sc;
    }
  const float inv = 1.f / lsum;
  float* dst = Og + ((size_t)bh * Mn + mt * 64 + row) * Dn + qc;
  *(f32x4*)&dst[0]  = acc0 * inv;
  *(f32x4*)&dst[4]  = acc1 * inv;
  *(f32x4*)&dst[8]  = acc2 * inv;
  *(f32x4*)&dst[12] = acc3 * inv;
}

// ---------------- fallback (round-1 kernel, passed @118us, no ws needed) ----------------

constexpr int ESTRIDE = 84;

__launch_bounds__(256, 2)
__global__ void stair_attn_fb(const float* __restrict__ Qg,
                              const float* __restrict__ Kg,
                              const float* __restrict__ Vg,
                              const float* __restrict__ PEg,
                              float* __restrict__ Og) {
  __shared__ __align__(16) unsigned short Kb[64 * 64];
  __shared__ __align__(16) unsigned short Vt[64 * 64];
  __shared__ __align__(16) unsigned short Pb[128 * 64];
  __shared__ __align__(16) float Elds[4 * 16 * ESTRIDE];
  __shared__ __align__(16) unsigned short Plds[4 * 16 * 64];

  const int tid = threadIdx.x;
  const int w = tid >> 6;
  const int lane = tid & 63;
  const int g = lane >> 4;
  const int q15 = lane & 15;

  const int bid = blockIdx.x;
  const int bh = bid & 15;
  const int jid = bid >> 4;
  const int mt = (jid < 16) ? (2 * jid) : (63 - 2 * jid);
  const int m0 = mt * 64;

  const float* Qb = Qg + (size_t)bh * Mn * Dn;
  const float* Kbase = Kg + (size_t)bh * Mn * Dn;
  const float* Vbase = Vg + (size_t)bh * Mn * Dn;
  float* Ob = Og + (size_t)bh * Mn * Dn;

  short8 aq[2];
  {
    const float* qp = Qb + (size_t)(m0 + 16 * w + q15) * Dn;
#pragma unroll
    for (int s = 0; s < 2; ++s) {
      const float4* p = (const float4*)(qp + s * 32 + g * 8);
      float4 f0 = p[0], f1 = p[1];
      short8 a;
      a[0]=(short)bfbits(f0.x); a[1]=(short)bfbits(f0.y); a[2]=(short)bfbits(f0.z); a[3]=(short)bfbits(f0.w);
      a[4]=(short)bfbits(f1.x); a[5]=(short)bfbits(f1.y); a[6]=(short)bfbits(f1.z); a[7]=(short)bfbits(f1.w);
      aq[s] = a;
    }
  }

  float mrun[4], lrun[4];
  f32x4 o[4] = {};
#pragma unroll
  for (int r = 0; r < 4; ++r) { mrun[r] = -1e30f; lrun[r] = 0.0f; }

  const int ntiles = mt + 1;
  const int dso = g * 8;

  for (int t = 0; t < ntiles; ++t) {
    const int l0 = t * 64;
    __syncthreads();
    {
      const int l = tid >> 2;
      const int dq = (tid & 3) * 16;
      const float* kp = Kbase + (size_t)(l0 + l) * Dn + dq;
      short8 u0, u1;
      {
        float4 f = ((const float4*)kp)[0];
        u0[0]=(short)bfbits(f.x); u0[1]=(short)bfbits(f.y); u0[2]=(short)bfbits(f.z); u0[3]=(short)bfbits(f.w);
        f = ((const float4*)kp)[1];
        u0[4]=(short)bfbits(f.x); u0[5]=(short)bfbits(f.y); u0[6]=(short)bfbits(f.z); u0[7]=(short)bfbits(f.w);
        f = ((const float4*)kp)[2];
        u1[0]=(short)bfbits(f.x); u1[1]=(short)bfbits(f.y); u1[2]=(short)bfbits(f.z); u1[3]=(short)bfbits(f.w);
        f = ((const float4*)kp)[3];
        u1[4]=(short)bfbits(f.x); u1[5]=(short)bfbits(f.y); u1[6]=(short)bfbits(f.z); u1[7]=(short)bfbits(f.w);
      }
      const int swz = (l & 7) << 3;
      *(short8*)&Kb[(l * 64 + dq) ^ swz] = u0;
      *(short8*)&Kb[(l * 64 + dq + 8) ^ swz] = u1;
    }
    {
      const int lrow = lane;
      const int ds = w * 16;
      const float* vp = Vbase + (size_t)(l0 + lrow) * Dn + ds;
#pragma unroll
      for (int i = 0; i < 4; ++i) {
        float4 f = ((const float4*)vp)[i];
        int c0 = ds + 4 * i;
        Vt[((c0 + 0) * 64 + lrow) ^ (((c0 + 0) & 7) << 3)] = bfbits(f.x);
        Vt[((c0 + 1) * 64 + lrow) ^ (((c0 + 1) & 7) << 3)] = bfbits(f.y);
        Vt[((c0 + 2) * 64 + lrow) ^ (((c0 + 2) & 7) << 3)] = bfbits(f.z);
        Vt[((c0 + 3) * 64 + lrow) ^ (((c0 + 3) & 7) << 3)] = bfbits(f.w);
      }
    }
    {
      const int d = lane;
      const int cc = w * 32;
      const int cb = (2048 - 64) - m0 + l0;
      const float* pp = PEg + (size_t)d * LIMn + (cb + cc);
      if (cb + cc + 31 < LIMn) {
#pragma unroll
        for (int i = 0; i < 8; ++i) {
          float4 f = ((const float4*)pp)[i];
          int c0 = cc + 4 * i;
          Pb[((c0 + 0) * 64 + d) ^ (((c0 + 0) & 7) << 3)] = bfbits(f.x);
          Pb[((c0 + 1) * 64 + d) ^ (((c0 + 1) & 7) << 3)] = bfbits(f.y);
          Pb[((c0 + 2) * 64 + d) ^ (((c0 + 2) & 7) << 3)] = bfbits(f.z);
          Pb[((c0 + 3) * 64 + d) ^ (((c0 + 3) & 7) << 3)] = bfbits(f.w);
        }
      } else {
        for (int i = 0; i < 32; ++i) {
          int cabs = cb + cc + i;
          float f = (cabs < LIMn) ? pp[i] : 0.0f;
          int c0 = cc + i;
          Pb[(c0 * 64 + d) ^ ((c0 & 7) << 3)] = bfbits(f);
        }
      }
    }
    __syncthreads();

    f32x4 qk[4] = {};
#pragma unroll
    for (int s = 0; s < 2; ++s)
#pragma unroll
      for (int nt = 0; nt < 4; ++nt) {
        int l = nt * 16 + q15;
        short8 b = *(short8*)&Kb[(l * 64 + s * 32 + dso) ^ ((l & 7) << 3)];
        qk[nt] = MFMA16(aq[s], b, qk[nt]);
      }

    f32x4 ev[5] = {};
    const int ntb = 3 - w;
#pragma unroll
    for (int s = 0; s < 2; ++s)
#pragma unroll
      for (int u5 = 0; u5 < 5; ++u5) {
        int c = (ntb + u5) * 16 + q15;
        short8 b = *(short8*)&Pb[(c * 64 + s * 32 + dso) ^ ((c & 7) << 3)];
        ev[u5] = MFMA16(aq[s], b, ev[u5]);
      }
    float* Ew = Elds + w * 16 * ESTRIDE;
#pragma unroll
    for (int u5 = 0; u5 < 5; ++u5)
#pragma unroll
      for (int r = 0; r < 4; ++r)
        Ew[(g * 4 + r) * ESTRIDE + u5 * 16 + q15] = ev[u5][r];

    const bool diag = (t == ntiles - 1);
    float sv[4][4];
#pragma unroll
    for (int nt = 0; nt < 4; ++nt) {
      int li = nt * 16 + q15;
#pragma unroll
      for (int r = 0; r < 4; ++r) {
        int rw = g * 4 + r;
        float eread = Ew[rw * ESTRIDE + (15 - rw + li)];
        bool masked = diag && (li > (16 * w + rw));
        sv[nt][r] = masked ? -1e30f : (qk[nt][r] + eread) * 0.125f;
      }
    }

    float mnew[4], alpha[4];
#pragma unroll
    for (int r = 0; r < 4; ++r) {
      float mx = fmaxf(fmaxf(sv[0][r], sv[1][r]), fmaxf(sv[2][r], sv[3][r]));
      mx = fmaxf(mx, __shfl_xor(mx, 1));
      mx = fmaxf(mx, __shfl_xor(mx, 2));
      mx = fmaxf(mx, __shfl_xor(mx, 4));
      mx = fmaxf(mx, __shfl_xor(mx, 8));
      float mn = fmaxf(mrun[r], mx);
      alpha[r] = exp2f((mrun[r] - mn) * 1.44269504f);
      mnew[r] = mn;
      mrun[r] = mn;
    }
    float pexp[4][4];
#pragma unroll
    for (int nt = 0; nt < 4; ++nt)
#pragma unroll
      for (int r = 0; r < 4; ++r)
        pexp[nt][r] = exp2f((sv[nt][r] - mnew[r]) * 1.44269504f);
#pragma unroll
    for (int r = 0; r < 4; ++r) {
      float sum = (pexp[0][r] + pexp[1][r]) + (pexp[2][r] + pexp[3][r]);
      sum += __shfl_xor(sum, 1);
      sum += __shfl_xor(sum, 2);
      sum += __shfl_xor(sum, 4);
      sum += __shfl_xor(sum, 8);
      lrun[r] = lrun[r] * alpha[r] + sum;
      o[0][r] *= alpha[r];
      o[1][r] *= alpha[r];
      o[2][r] *= alpha[r];
      o[3][r] *= alpha[r];
    }

    unsigned short* Pw = Plds + w * 16 * 64;
#pragma unroll
    for (int nt = 0; nt < 4; ++nt)
#pragma unroll
      for (int r = 0; r < 4; ++r) {
        int rw = g * 4 + r;
        Pw[(rw * 64 + nt * 16 + q15) ^ ((rw & 7) << 3)] = bfbits(pexp[nt][r]);
      }
    short8 pa[2];
#pragma unroll
    for (int s = 0; s < 2; ++s)
      pa[s] = *(short8*)&Pw[(q15 * 64 + s * 32 + dso) ^ ((q15 & 7) << 3)];

#pragma unroll
    for (int s = 0; s < 2; ++s)
#pragma unroll
      for (int nt = 0; nt < 4; ++nt) {
        int d = nt * 16 + q15;
        short8 b = *(short8*)&Vt[(d * 64 + s * 32 + dso) ^ ((d & 7) << 3)];
        o[nt] = MFMA16(pa[s], b, o[nt]);
      }
  }

#pragma unroll
  for (int nt = 0; nt < 4; ++nt)
#pragma unroll
    for (int r = 0; r < 4; ++r) {
      int m = m0 + 16 * w + g * 4 + r;
      Ob[(size_t)m * Dn + nt * 16 + q15] = o[nt][r] / lrun[r];
    }
}

// ---------------- launch ----------------

extern "C" void kernel_launch(void* const* d_in, const int* in_sizes, int n_in,
                              void* d_out, int out_size, void* d_ws, size_t ws_size,
                              hipStream_t stream) {
  (void)in_sizes; (void)n_in; (void)out_size;
  const float* Q  = (const float*)d_in[0];
  const float* K  = (const float*)d_in[1];
  const float* V  = (const float*)d_in[2];
  const float* PE = (const float*)d_in[3];
  float* Out = (float*)d_out;

  const size_t szK = KF_SHORTS * sizeof(unsigned short);              // 4 MB
  const size_t szV = szK;                                              // 4 MB
  const size_t szP = PEF_SHORTS * sizeof(unsigned short);              // 264 KB
  const size_t szPart = (size_t)BH * SLOTS_PER_HEAD * PART_SLOT * 4;   // 19.5 MB
  const size_t need1 = szK + szV + szP;
  const size_t need2 = need1 + szPart;

  if (ws_size >= need1) {
    unsigned short* Kf  = (unsigned short*)d_ws;
    unsigned short* Vf  = (unsigned short*)((char*)d_ws + szK);
    unsigned short* PEf = (unsigned short*)((char*)d_ws + szK + szV);
    float* Part = (float*)((char*)d_ws + need1);

    hipLaunchKernelGGL(prep_all, dim3(512 + 33), dim3(256), 0, stream, K, V, PE, Kf, Vf, PEf);
    if (ws_size >= need2) {
      hipLaunchKernelGGL(stair_main, dim3(BH * 80), dim3(256), 0, stream,
                         Q, Kf, Vf, PEf, Out, Part, 1);
      hipLaunchKernelGGL(combine_parts, dim3(BH * 24), dim3(256), 0, stream, Part, Out);
    } else {
      hipLaunchKernelGGL(stair_main, dim3(512), dim3(256), 0, stream,
                         Q, Kf, Vf, PEf, Out, (float*)d_ws, 0);
    }
  } else {
    hipLaunchKernelGGL(stair_attn_fb, dim3(512), dim3(256), 0, stream, Q, K, V, PE, Out);
  }
}

// Round 5
// 78.967 us; speedup vs baseline: 2.6763x; 1.1165x over previous
//
#include <hip/hip_runtime.h>
#include <hip/hip_bf16.h>

typedef __attribute__((ext_vector_type(8))) short short8;
typedef __attribute__((ext_vector_type(4))) float f32x4;

#define MFMA16(A, B, C) __builtin_amdgcn_mfma_f32_16x16x32_bf16((A), (B), (C), 0, 0, 0)

#define GL16(gp, lp) __builtin_amdgcn_global_load_lds( \
    (const __attribute__((address_space(1))) void*)(gp), \
    (__attribute__((address_space(3))) void*)(lp), 16, 0, 0)

__device__ __forceinline__ unsigned short bfbits(float f) {
  return __builtin_bit_cast(unsigned short, (__bf16)f);
}

constexpr int BH = 16;
constexpr int Mn = 2048;
constexpr int Dn = 64;
constexpr int LIMn = 2048;
constexpr size_t KF_SHORTS = (size_t)BH * 32 * 8 * 512;
constexpr size_t PE_JROWS = 132;
constexpr size_t PEF_SHORTS = PE_JROWS * 2 * 512;
constexpr int PART_SLOT = 4224;        // 64*64 o + 64 m + 64 l floats
constexpr int SLOTS_PER_HEAD = 72;     // sum of chunks for mt=8..31

__device__ __forceinline__ int part_offs(int mt) {
  return (mt < 16) ? 2 * (mt - 8) : (mt < 24 ? 16 + 3 * (mt - 16) : 40 + 4 * (mt - 24));
}

// ---------------- prep: fp32 -> bf16 MFMA-fragment-tiled layouts (verified r3/r4) ----------------

__global__ void prep_all(const float* __restrict__ K, const float* __restrict__ V,
                         const float* __restrict__ PE,
                         unsigned short* __restrict__ Kf, unsigned short* __restrict__ Vf,
                         unsigned short* __restrict__ PEf) {
  __shared__ float tA[64 * 64];
  __shared__ float tB[64 * 64];
  const int b = blockIdx.x, tid = threadIdx.x;
  const int w = tid >> 6, lane = tid & 63, g = lane >> 4, q15 = lane & 15;

  if (b < 512) {
    const int bh = b >> 5, lt = b & 31;
    const float* Ks = K + ((size_t)bh * Mn + lt * 64) * Dn;
    const float* Vs = V + ((size_t)bh * Mn + lt * 64) * Dn;
    const int row = tid >> 2, c0 = (tid & 3) * 16;
#pragma unroll
    for (int i = 0; i < 4; ++i) {
      *(float4*)&tA[row * 64 + c0 + 4 * i] = ((const float4*)(Ks + (size_t)row * 64 + c0))[i];
      *(float4*)&tB[row * 64 + c0 + 4 * i] = ((const float4*)(Vs + (size_t)row * 64 + c0))[i];
    }
    __syncthreads();
#pragma unroll
    for (int i = 0; i < 2; ++i) {
      const int f = 2 * w + i, nt = f >> 1, s = f & 1;
      short8 uk, uv;
#pragma unroll
      for (int j = 0; j < 8; ++j) {
        uk[j] = (short)bfbits(tA[(nt * 16 + q15) * 64 + s * 32 + g * 8 + j]);
        uv[j] = (short)bfbits(tB[(s * 32 + g * 8 + j) * 64 + nt * 16 + q15]);
      }
      const size_t base = ((size_t)(bh * 32 + lt) * 8 + f) * 512 + lane * 8;
      *(short8*)&Kf[base] = uk;
      *(short8*)&Vf[base] = uv;
    }
  } else {
    const int pb = b - 512;
    const int c0 = pb * 64;
    const int d = tid >> 2, cc = (tid & 3) * 16;
#pragma unroll
    for (int i = 0; i < 16; ++i) {
      const int c = c0 + cc + i;
      tA[(cc + i) * 64 + d] = (c < LIMn) ? PE[(size_t)d * LIMn + c] : 0.0f;
    }
    __syncthreads();
#pragma unroll
    for (int s = 0; s < 2; ++s) {
      short8 u;
#pragma unroll
      for (int j = 0; j < 8; ++j)
        u[j] = (short)bfbits(tA[(w * 16 + q15) * 64 + s * 32 + g * 8 + j]);
      *(short8*)&PEf[((size_t)(4 * pb + w) * 2 + s) * 512 + lane * 8] = u;
    }
  }
}

// ---------------- main: pair-tile fused online softmax (BL=128 steps), split-K ----------------

__launch_bounds__(256)
__global__ void stair_main(const float* __restrict__ Qg,
                           const unsigned short* __restrict__ Kf,
                           const unsigned short* __restrict__ Vf,
                           const unsigned short* __restrict__ PEf,
                           float* __restrict__ Og,
                           float* __restrict__ Part,
                           int split) {
  __shared__ __align__(16) unsigned short Kbuf[2][2][4096];  // [dbuf][tileslot][frags]
  __shared__ __align__(16) unsigned short Vbuf[2][2][4096];
  __shared__ __align__(16) unsigned short Plds[4][2048];     // per-wave, 2 tile slots

  const int tid = threadIdx.x;
  const int w = tid >> 6, lane = tid & 63, g = lane >> 4, q15 = lane & 15;
  const int bid = blockIdx.x;

  int bh, mt, chunk, t0, t1, nch;
  bh = bid & 15;                       // head -> fixed XCD: K/V L2-resident
  if (split) {
    const int u = bid >> 4;            // 0..79, heavy-first
    if (u < 32)      { mt = 31 - (u >> 2); chunk = u & 3; }
    else if (u < 56) { const int v = u - 32, q = v / 3; mt = 23 - q; chunk = v - q * 3; }
    else if (u < 72) { const int v = u - 56; mt = 15 - (v >> 1); chunk = v & 1; }
    else             { mt = 7 - (u - 72); chunk = 0; }
    t0 = chunk * 8;
    t1 = (t0 + 8 < mt + 1) ? (t0 + 8) : (mt + 1);
    nch = (mt + 8) >> 3;
  } else {
    mt = 31 - (bid >> 4); chunk = 0; t0 = 0; t1 = mt + 1; nch = 1;
  }
  const int m0w = mt * 64 + w * 16;

  const float* Qb = Qg + (size_t)bh * Mn * Dn;
  float* Ob = Og + (size_t)bh * Mn * Dn;

  // Q A-fragments
  short8 aq[2];
  {
    const float* qp = Qb + (size_t)(m0w + q15) * Dn;
#pragma unroll
    for (int s = 0; s < 2; ++s) {
      const float4* p = (const float4*)(qp + s * 32 + g * 8);
      float4 f0 = p[0], f1 = p[1];
      short8 a;
      a[0]=(short)bfbits(f0.x); a[1]=(short)bfbits(f0.y); a[2]=(short)bfbits(f0.z); a[3]=(short)bfbits(f0.w);
      a[4]=(short)bfbits(f1.x); a[5]=(short)bfbits(f1.y); a[6]=(short)bfbits(f1.z); a[7]=(short)bfbits(f1.w);
      aq[s] = a;
    }
  }

  float mrun[4], lrun[4];
  f32x4 o[4] = {};
#pragma unroll
  for (int r = 0; r < 4; ++r) { mrun[r] = -1e30f; lrun[r] = 0.0f; }

  // stage one tile's K/V frags into (buf, slot)
  auto STAGE1 = [&](int b, int slot, int t) {
    const size_t toff = ((size_t)(bh * 32 + t) * 8) * 512;
#pragma unroll
    for (int i = 0; i < 2; ++i) {
      const int f = 2 * w + i;
      const size_t off = toff + (size_t)f * 512 + lane * 8;
      GL16(&Kf[off], &Kbuf[b][slot][f * 512]);
      GL16(&Vf[off], &Vbuf[b][slot][f * 512]);
    }
  };

  // QK^T for one tile slot
  auto QK = [&](f32x4 qk[4], int cur, int slot, int ntmax) {
#pragma unroll
    for (int s = 0; s < 2; ++s)
#pragma unroll
      for (int nt = 0; nt < 4; ++nt)
        if (nt <= ntmax) {
          short8 bfr = *(const short8*)&Kbuf[cur][slot][(nt * 2 + s) * 512 + lane * 8];
          qk[nt] = MFMA16(aq[s], bfr, qk[nt]);
        }
  };

  // diagonal gather (verified r2-r4): sv from qk + shuffled ev
  auto GATHER = [&](float sv[4][4], const f32x4 qk[4], const f32x4 ev[5],
                    int ntmax, bool diag) {
#pragma unroll
    for (int nt = 0; nt < 4; ++nt)
      if (nt <= ntmax) {
#pragma unroll
        for (int r = 0; r < 4; ++r) {
          const int rw = g * 4 + r;
          const int srcLane = (lane & 48) | ((q15 + 15 - rw) & 15);
          float e_lo = __shfl(ev[nt][r], srcLane, 64);
          float e_hi = __shfl(ev[nt + 1][r], srcLane, 64);
          float er = (q15 > rw) ? e_hi : e_lo;
          const int li = nt * 16 + q15;
          bool masked = diag && (li > w * 16 + rw);
          sv[nt][r] = masked ? -1e30f : (qk[nt][r] + er) * 0.125f;
        }
      }
  };

  // P bounce + PV for one tile slot
  auto PV = [&](const float sv[4][4], int cur, int slot, int smax) {
#pragma unroll
    for (int nt = 0; nt < 4; ++nt)
#pragma unroll
      for (int r = 0; r < 4; ++r) {
        const int rw = g * 4 + r;
        Plds[w][slot * 1024 + ((rw * 64 + nt * 16 + q15) ^ ((rw & 7) << 3))] = bfbits(sv[nt][r]);
      }
    short8 pa[2];
#pragma unroll
    for (int s = 0; s < 2; ++s)
      if (s <= smax)
        pa[s] = *(short8*)&Plds[w][slot * 1024 + ((q15 * 64 + s * 32 + g * 8) ^ ((q15 & 7) << 3))];
#pragma unroll
    for (int s = 0; s < 2; ++s)
      if (s <= smax)
#pragma unroll
        for (int nt = 0; nt < 4; ++nt) {
          short8 bfr = *(const short8*)&Vbuf[cur][slot][(nt * 2 + s) * 512 + lane * 8];
          o[nt] = MFMA16(pa[s], bfr, o[nt]);
        }
  };

  // ---- pair body: one online-softmax step over 128 columns ----
  auto PAIR = [&](int t, int cur, bool diagB) {
    const int jbA = 127 - 4 * mt - w + 4 * t;
    const int jbB = jbA + 4;
    const int ntmaxB = diagB ? w : 3;
    const int u5B = diagB ? (w + 2) : 5;
    const int smaxB = diagB ? (w >> 1) : 1;

    // issue PE loads early (L2-hot; latency hides under K ds_read + QK MFMA)
    short8 peA[2][5], peB[2][5];
#pragma unroll
    for (int s = 0; s < 2; ++s)
#pragma unroll
      for (int u = 0; u < 5; ++u) {
        peA[s][u] = *(const short8*)&PEf[((size_t)(jbA + u) * 2 + s) * 512 + lane * 8];
        if (u < u5B)
          peB[s][u] = *(const short8*)&PEf[((size_t)(jbB + u) * 2 + s) * 512 + lane * 8];
      }

    f32x4 qkA[4] = {}, qkB[4] = {};
    QK(qkA, cur, 0, 3);
    QK(qkB, cur, 1, ntmaxB);

    // E_A MFMAs, then gather A overlaps E_B MFMAs (LDS pipe vs MFMA pipe)
    f32x4 evA[5] = {};
#pragma unroll
    for (int s = 0; s < 2; ++s)
#pragma unroll
      for (int u = 0; u < 5; ++u) evA[u] = MFMA16(aq[s], peA[s][u], evA[u]);

    float svA[4][4], svB[4][4];
#pragma unroll
    for (int nt = 0; nt < 4; ++nt)
#pragma unroll
      for (int r = 0; r < 4; ++r) { svA[nt][r] = -1e30f; svB[nt][r] = -1e30f; }

    GATHER(svA, qkA, evA, 3, false);

    f32x4 evB[5] = {};
#pragma unroll
    for (int s = 0; s < 2; ++s)
#pragma unroll
      for (int u = 0; u < 5; ++u)
        if (u < u5B) evB[u] = MFMA16(aq[s], peB[s][u], evB[u]);

    GATHER(svB, qkB, evB, ntmaxB, diagB);

    // joint defer-max online softmax over 128 cols
    float lmax[4];
#pragma unroll
    for (int r = 0; r < 4; ++r) {
      float a = fmaxf(fmaxf(svA[0][r], svA[1][r]), fmaxf(svA[2][r], svA[3][r]));
      float b = fmaxf(fmaxf(svB[0][r], svB[1][r]), fmaxf(svB[2][r], svB[3][r]));
      lmax[r] = fmaxf(a, b);
    }
    const bool fast = __all((lmax[0] <= mrun[0] + 8.f) & (lmax[1] <= mrun[1] + 8.f) &
                            (lmax[2] <= mrun[2] + 8.f) & (lmax[3] <= mrun[3] + 8.f));
    if (!fast) {
#pragma unroll
      for (int r = 0; r < 4; ++r) {
        float mx = lmax[r];
        mx = fmaxf(mx, __shfl_xor(mx, 1));
        mx = fmaxf(mx, __shfl_xor(mx, 2));
        mx = fmaxf(mx, __shfl_xor(mx, 4));
        mx = fmaxf(mx, __shfl_xor(mx, 8));
        const float mn = fmaxf(mrun[r], mx);
        const float alpha = exp2f((mrun[r] - mn) * 1.44269504f);
        mrun[r] = mn;
        lrun[r] *= alpha;
        o[0][r] *= alpha; o[1][r] *= alpha; o[2][r] *= alpha; o[3][r] *= alpha;
      }
    }
#pragma unroll
    for (int nt = 0; nt < 4; ++nt)
#pragma unroll
      for (int r = 0; r < 4; ++r) {
        svA[nt][r] = exp2f((svA[nt][r] - mrun[r]) * 1.44269504f);
        svB[nt][r] = exp2f((svB[nt][r] - mrun[r]) * 1.44269504f);
      }
#pragma unroll
    for (int r = 0; r < 4; ++r) {
      float sum = ((svA[0][r] + svA[1][r]) + (svA[2][r] + svA[3][r])) +
                  ((svB[0][r] + svB[1][r]) + (svB[2][r] + svB[3][r]));
      sum += __shfl_xor(sum, 1);
      sum += __shfl_xor(sum, 2);
      sum += __shfl_xor(sum, 4);
      sum += __shfl_xor(sum, 8);
      lrun[r] += sum;
    }

    PV(svA, cur, 0, 1);
    PV(svB, cur, 1, smaxB);
  };

  // ---- single-tile body (chunk remainder) ----
  auto SINGLE = [&](int t, int cur, bool diag) {
    const int jb = 127 - 4 * mt - w + 4 * t;
    const int ntmax = diag ? w : 3;
    const int u5 = diag ? (w + 2) : 5;
    const int smax = diag ? (w >> 1) : 1;

    short8 pe[2][5];
#pragma unroll
    for (int s = 0; s < 2; ++s)
#pragma unroll
      for (int u = 0; u < 5; ++u)
        if (u < u5)
          pe[s][u] = *(const short8*)&PEf[((size_t)(jb + u) * 2 + s) * 512 + lane * 8];

    f32x4 qk[4] = {};
    QK(qk, cur, 0, ntmax);
    f32x4 ev[5] = {};
#pragma unroll
    for (int s = 0; s < 2; ++s)
#pragma unroll
      for (int u = 0; u < 5; ++u)
        if (u < u5) ev[u] = MFMA16(aq[s], pe[s][u], ev[u]);

    float sv[4][4];
#pragma unroll
    for (int nt = 0; nt < 4; ++nt)
#pragma unroll
      for (int r = 0; r < 4; ++r) sv[nt][r] = -1e30f;
    GATHER(sv, qk, ev, ntmax, diag);

    float lmax[4];
#pragma unroll
    for (int r = 0; r < 4; ++r)
      lmax[r] = fmaxf(fmaxf(sv[0][r], sv[1][r]), fmaxf(sv[2][r], sv[3][r]));
    const bool fast = __all((lmax[0] <= mrun[0] + 8.f) & (lmax[1] <= mrun[1] + 8.f) &
                            (lmax[2] <= mrun[2] + 8.f) & (lmax[3] <= mrun[3] + 8.f));
    if (!fast) {
#pragma unroll
      for (int r = 0; r < 4; ++r) {
        float mx = lmax[r];
        mx = fmaxf(mx, __shfl_xor(mx, 1));
        mx = fmaxf(mx, __shfl_xor(mx, 2));
        mx = fmaxf(mx, __shfl_xor(mx, 4));
        mx = fmaxf(mx, __shfl_xor(mx, 8));
        const float mn = fmaxf(mrun[r], mx);
        const float alpha = exp2f((mrun[r] - mn) * 1.44269504f);
        mrun[r] = mn;
        lrun[r] *= alpha;
        o[0][r] *= alpha; o[1][r] *= alpha; o[2][r] *= alpha; o[3][r] *= alpha;
      }
    }
#pragma unroll
    for (int nt = 0; nt < 4; ++nt)
#pragma unroll
      for (int r = 0; r < 4; ++r)
        sv[nt][r] = exp2f((sv[nt][r] - mrun[r]) * 1.44269504f);
#pragma unroll
    for (int r = 0; r < 4; ++r) {
      float sum = (sv[0][r] + sv[1][r]) + (sv[2][r] + sv[3][r]);
      sum += __shfl_xor(sum, 1);
      sum += __shfl_xor(sum, 2);
      sum += __shfl_xor(sum, 4);
      sum += __shfl_xor(sum, 8);
      lrun[r] += sum;
    }
    PV(sv, cur, 0, smax);
  };

  // ---- main loop over pairs ----
  {
    int cur = 0;
    int t = t0;
    const int n0 = (t1 - t0 >= 2) ? 2 : 1;
    STAGE1(0, 0, t0);
    if (n0 == 2) STAGE1(0, 1, t0 + 1);
    __syncthreads();
    while (t < t1) {
      const int n = (t1 - t >= 2) ? 2 : 1;
      const int rem = t1 - (t + n);
      const int nn = (rem >= 2) ? 2 : rem;
      if (nn > 0) {
        STAGE1(cur ^ 1, 0, t + n);
        if (nn == 2) STAGE1(cur ^ 1, 1, t + n + 1);
      }
      if (n == 2) PAIR(t, cur, (t + 1 == mt));
      else SINGLE(t, cur, (t == mt));
      if (nn > 0) __syncthreads();
      cur ^= 1;
      t += n;
    }
  }

  // epilogue
  if (nch == 1) {
#pragma unroll
    for (int nt = 0; nt < 4; ++nt)
#pragma unroll
      for (int r = 0; r < 4; ++r) {
        const int m = m0w + g * 4 + r;
        Ob[(size_t)m * Dn + nt * 16 + q15] = o[nt][r] / lrun[r];
      }
  } else {
    float* ps = Part + ((size_t)bh * SLOTS_PER_HEAD + part_offs(mt) + chunk) * PART_SLOT;
#pragma unroll
    for (int nt = 0; nt < 4; ++nt)
#pragma unroll
      for (int r = 0; r < 4; ++r)
        ps[(w * 16 + g * 4 + r) * 64 + nt * 16 + q15] = o[nt][r];
#pragma unroll
    for (int r = 0; r < 4; ++r)
      if (q15 == g * 4 + r) {
        ps[4096 + w * 16 + q15] = mrun[r];
        ps[4160 + w * 16 + q15] = lrun[r];
      }
  }
}

// ---------------- combine: merge 2-4 chunk partials per (head, mtile>=8) ----------------

__launch_bounds__(256, 4)
__global__ void combine_parts(const float* __restrict__ Part, float* __restrict__ Og) {
  const int bid = blockIdx.x;
  const int bh = bid & 15;
  const int mt = 8 + (bid >> 4);
  const int nch = (mt + 8) >> 3;
  const float* base = Part + ((size_t)bh * SLOTS_PER_HEAD + part_offs(mt)) * PART_SLOT;
  const int tid = threadIdx.x;
  const int row = tid >> 2;
  const int qc = (tid & 3) * 16;

  float mstar = -1e30f;
#pragma unroll
  for (int c = 0; c < 4; ++c)
    if (c < nch) mstar = fmaxf(mstar, base[c * PART_SLOT + 4096 + row]);
  float lsum = 0.f;
  f32x4 acc0 = {}, acc1 = {}, acc2 = {}, acc3 = {};
#pragma unroll
  for (int c = 0; c < 4; ++c)
    if (c < nch) {
      const float* ps = base + c * PART_SLOT;
      const float sc = exp2f((ps[4096 + row] - mstar) * 1.44269504f);
      lsum += ps[4160 + row] * sc;
      const f32x4* op = (const f32x4*)&ps[row * 64 + qc];
      acc0 += op[0] * sc; acc1 += op[1] * sc; acc2 += op[2] * sc; acc3 += op[3] * sc;
    }
  const float inv = 1.f / lsum;
  float* dst = Og + ((size_t)bh * Mn + mt * 64 + row) * Dn + qc;
  *(f32x4*)&dst[0]  = acc0 * inv;
  *(f32x4*)&dst[4]  = acc1 * inv;
  *(f32x4*)&dst[8]  = acc2 * inv;
  *(f32x4*)&dst[12] = acc3 * inv;
}

// ---------------- fallback (round-1 kernel, passed @118us, no ws needed) ----------------

constexpr int ESTRIDE = 84;

__launch_bounds__(256, 2)
__global__ void stair_attn_fb(const float* __restrict__ Qg,
                              const float* __restrict__ Kg,
                              const float* __restrict__ Vg,
                              const float* __restrict__ PEg,
                              float* __restrict__ Og) {
  __shared__ __align__(16) unsigned short Kb[64 * 64];
  __shared__ __align__(16) unsigned short Vt[64 * 64];
  __shared__ __align__(16) unsigned short Pb[128 * 64];
  __shared__ __align__(16) float Elds[4 * 16 * ESTRIDE];
  __shared__ __align__(16) unsigned short Plds[4 * 16 * 64];

  const int tid = threadIdx.x;
  const int w = tid >> 6;
  const int lane = tid & 63;
  const int g = lane >> 4;
  const int q15 = lane & 15;

  const int bid = blockIdx.x;
  const int bh = bid & 15;
  const int jid = bid >> 4;
  const int mt = (jid < 16) ? (2 * jid) : (63 - 2 * jid);
  const int m0 = mt * 64;

  const float* Qb = Qg + (size_t)bh * Mn * Dn;
  const float* Kbase = Kg + (size_t)bh * Mn * Dn;
  const float* Vbase = Vg + (size_t)bh * Mn * Dn;
  float* Ob = Og + (size_t)bh * Mn * Dn;

  short8 aq[2];
  {
    const float* qp = Qb + (size_t)(m0 + 16 * w + q15) * Dn;
#pragma unroll
    for (int s = 0; s < 2; ++s) {
      const float4* p = (const float4*)(qp + s * 32 + g * 8);
      float4 f0 = p[0], f1 = p[1];
      short8 a;
      a[0]=(short)bfbits(f0.x); a[1]=(short)bfbits(f0.y); a[2]=(short)bfbits(f0.z); a[3]=(short)bfbits(f0.w);
      a[4]=(short)bfbits(f1.x); a[5]=(short)bfbits(f1.y); a[6]=(short)bfbits(f1.z); a[7]=(short)bfbits(f1.w);
      aq[s] = a;
    }
  }

  float mrun[4], lrun[4];
  f32x4 o[4] = {};
#pragma unroll
  for (int r = 0; r < 4; ++r) { mrun[r] = -1e30f; lrun[r] = 0.0f; }

  const int ntiles = mt + 1;
  const int dso = g * 8;

  for (int t = 0; t < ntiles; ++t) {
    const int l0 = t * 64;
    __syncthreads();
    {
      const int l = tid >> 2;
      const int dq = (tid & 3) * 16;
      const float* kp = Kbase + (size_t)(l0 + l) * Dn + dq;
      short8 u0, u1;
      {
        float4 f = ((const float4*)kp)[0];
        u0[0]=(short)bfbits(f.x); u0[1]=(short)bfbits(f.y); u0[2]=(short)bfbits(f.z); u0[3]=(short)bfbits(f.w);
        f = ((const float4*)kp)[1];
        u0[4]=(short)bfbits(f.x); u0[5]=(short)bfbits(f.y); u0[6]=(short)bfbits(f.z); u0[7]=(short)bfbits(f.w);
        f = ((const float4*)kp)[2];
        u1[0]=(short)bfbits(f.x); u1[1]=(short)bfbits(f.y); u1[2]=(short)bfbits(f.z); u1[3]=(short)bfbits(f.w);
        f = ((const float4*)kp)[3];
        u1[4]=(short)bfbits(f.x); u1[5]=(short)bfbits(f.y); u1[6]=(short)bfbits(f.z); u1[7]=(short)bfbits(f.w);
      }
      const int swz = (l & 7) << 3;
      *(short8*)&Kb[(l * 64 + dq) ^ swz] = u0;
      *(short8*)&Kb[(l * 64 + dq + 8) ^ swz] = u1;
    }
    {
      const int lrow = lane;
      const int ds = w * 16;
      const float* vp = Vbase + (size_t)(l0 + lrow) * Dn + ds;
#pragma unroll
      for (int i = 0; i < 4; ++i) {
        float4 f = ((const float4*)vp)[i];
        int c0 = ds + 4 * i;
        Vt[((c0 + 0) * 64 + lrow) ^ (((c0 + 0) & 7) << 3)] = bfbits(f.x);
        Vt[((c0 + 1) * 64 + lrow) ^ (((c0 + 1) & 7) << 3)] = bfbits(f.y);
        Vt[((c0 + 2) * 64 + lrow) ^ (((c0 + 2) & 7) << 3)] = bfbits(f.z);
        Vt[((c0 + 3) * 64 + lrow) ^ (((c0 + 3) & 7) << 3)] = bfbits(f.w);
      }
    }
    {
      const int d = lane;
      const int cc = w * 32;
      const int cb = (2048 - 64) - m0 + l0;
      const float* pp = PEg + (size_t)d * LIMn + (cb + cc);
      if (cb + cc + 31 < LIMn) {
#pragma unroll
        for (int i = 0; i < 8; ++i) {
          float4 f = ((const float4*)pp)[i];
          int c0 = cc + 4 * i;
          Pb[((c0 + 0) * 64 + d) ^ (((c0 + 0) & 7) << 3)] = bfbits(f.x);
          Pb[((c0 + 1) * 64 + d) ^ (((c0 + 1) & 7) << 3)] = bfbits(f.y);
          Pb[((c0 + 2) * 64 + d) ^ (((c0 + 2) & 7) << 3)] = bfbits(f.z);
          Pb[((c0 + 3) * 64 + d) ^ (((c0 + 3) & 7) << 3)] = bfbits(f.w);
        }
      } else {
        for (int i = 0; i < 32; ++i) {
          int cabs = cb + cc + i;
          float f = (cabs < LIMn) ? pp[i] : 0.0f;
          int c0 = cc + i;
          Pb[(c0 * 64 + d) ^ ((c0 & 7) << 3)] = bfbits(f);
        }
      }
    }
    __syncthreads();

    f32x4 qk[4] = {};
#pragma unroll
    for (int s = 0; s < 2; ++s)
#pragma unroll
      for (int nt = 0; nt < 4; ++nt) {
        int l = nt * 16 + q15;
        short8 b = *(short8*)&Kb[(l * 64 + s * 32 + dso) ^ ((l & 7) << 3)];
        qk[nt] = MFMA16(aq[s], b, qk[nt]);
      }

    f32x4 ev[5] = {};
    const int ntb = 3 - w;
#pragma unroll
    for (int s = 0; s < 2; ++s)
#pragma unroll
      for (int u5 = 0; u5 < 5; ++u5) {
        int c = (ntb + u5) * 16 + q15;
        short8 b = *(short8*)&Pb[(c * 64 + s * 32 + dso) ^ ((c & 7) << 3)];
        ev[u5] = MFMA16(aq[s], b, ev[u5]);
      }
    float* Ew = Elds + w * 16 * ESTRIDE;
#pragma unroll
    for (int u5 = 0; u5 < 5; ++u5)
#pragma unroll
      for (int r = 0; r < 4; ++r)
        Ew[(g * 4 + r) * ESTRIDE + u5 * 16 + q15] = ev[u5][r];

    const bool diag = (t == ntiles - 1);
    float sv[4][4];
#pragma unroll
    for (int nt = 0; nt < 4; ++nt) {
      int li = nt * 16 + q15;
#pragma unroll
      for (int r = 0; r < 4; ++r) {
        int rw = g * 4 + r;
        float eread = Ew[rw * ESTRIDE + (15 - rw + li)];
        bool masked = diag && (li > (16 * w + rw));
        sv[nt][r] = masked ? -1e30f : (qk[nt][r] + eread) * 0.125f;
      }
    }

    float mnew[4], alpha[4];
#pragma unroll
    for (int r = 0; r < 4; ++r) {
      float mx = fmaxf(fmaxf(sv[0][r], sv[1][r]), fmaxf(sv[2][r], sv[3][r]));
      mx = fmaxf(mx, __shfl_xor(mx, 1));
      mx = fmaxf(mx, __shfl_xor(mx, 2));
      mx = fmaxf(mx, __shfl_xor(mx, 4));
      mx = fmaxf(mx, __shfl_xor(mx, 8));
      float mn = fmaxf(mrun[r], mx);
      alpha[r] = exp2f((mrun[r] - mn) * 1.44269504f);
      mnew[r] = mn;
      mrun[r] = mn;
    }
    float pexp[4][4];
#pragma unroll
    for (int nt = 0; nt < 4; ++nt)
#pragma unroll
      for (int r = 0; r < 4; ++r)
        pexp[nt][r] = exp2f((sv[nt][r] - mnew[r]) * 1.44269504f);
#pragma unroll
    for (int r = 0; r < 4; ++r) {
      float sum = (pexp[0][r] + pexp[1][r]) + (pexp[2][r] + pexp[3][r]);
      sum += __shfl_xor(sum, 1);
      sum += __shfl_xor(sum, 2);
      sum += __shfl_xor(sum, 4);
      sum += __shfl_xor(sum, 8);
      lrun[r] = lrun[r] * alpha[r] + sum;
      o[0][r] *= alpha[r];
      o[1][r] *= alpha[r];
      o[2][r] *= alpha[r];
      o[3][r] *= alpha[r];
    }

    unsigned short* Pw = Plds + w * 16 * 64;
#pragma unroll
    for (int nt = 0; nt < 4; ++nt)
#pragma unroll
      for (int r = 0; r < 4; ++r) {
        int rw = g * 4 + r;
        Pw[(rw * 64 + nt * 16 + q15) ^ ((rw & 7) << 3)] = bfbits(pexp[nt][r]);
      }
    short8 pa[2];
#pragma unroll
    for (int s = 0; s < 2; ++s)
      pa[s] = *(short8*)&Pw[(q15 * 64 + s * 32 + dso) ^ ((q15 & 7) << 3)];

#pragma unroll
    for (int s = 0; s < 2; ++s)
#pragma unroll
      for (int nt = 0; nt < 4; ++nt) {
        int d = nt * 16 + q15;
        short8 b = *(short8*)&Vt[(d * 64 + s * 32 + dso) ^ ((d & 7) << 3)];
        o[nt] = MFMA16(pa[s], b, o[nt]);
      }
  }

#pragma unroll
  for (int nt = 0; nt < 4; ++nt)
#pragma unroll
    for (int r = 0; r < 4; ++r) {
      int m = m0 + 16 * w + g * 4 + r;
      Ob[(size_t)m * Dn + nt * 16 + q15] = o[nt][r] / lrun[r];
    }
}

// ---------------- launch ----------------

extern "C" void kernel_launch(void* const* d_in, const int* in_sizes, int n_in,
                              void* d_out, int out_size, void* d_ws, size_t ws_size,
                              hipStream_t stream) {
  (void)in_sizes; (void)n_in; (void)out_size;
  const float* Q  = (const float*)d_in[0];
  const float* K  = (const float*)d_in[1];
  const float* V  = (const float*)d_in[2];
  const float* PE = (const float*)d_in[3];
  float* Out = (float*)d_out;

  const size_t szK = KF_SHORTS * sizeof(unsigned short);              // 4 MB
  const size_t szV = szK;                                              // 4 MB
  const size_t szP = PEF_SHORTS * sizeof(unsigned short);              // 264 KB
  const size_t szPart = (size_t)BH * SLOTS_PER_HEAD * PART_SLOT * 4;   // 19.5 MB
  const size_t need1 = szK + szV + szP;
  const size_t need2 = need1 + szPart;

  if (ws_size >= need1) {
    unsigned short* Kf  = (unsigned short*)d_ws;
    unsigned short* Vf  = (unsigned short*)((char*)d_ws + szK);
    unsigned short* PEf = (unsigned short*)((char*)d_ws + szK + szV);
    float* Part = (float*)((char*)d_ws + need1);

    hipLaunchKernelGGL(prep_all, dim3(512 + 33), dim3(256), 0, stream, K, V, PE, Kf, Vf, PEf);
    if (ws_size >= need2) {
      hipLaunchKernelGGL(stair_main, dim3(BH * 80), dim3(256), 0, stream,
                         Q, Kf, Vf, PEf, Out, Part, 1);
      hipLaunchKernelGGL(combine_parts, dim3(BH * 24), dim3(256), 0, stream, Part, Out);
    } else {
      hipLaunchKernelGGL(stair_main, dim3(512), dim3(256), 0, stream,
                         Q, Kf, Vf, PEf, Out, (float*)d_ws, 0);
    }
  } else {
    hipLaunchKernelGGL(stair_attn_fb, dim3(512), dim3(256), 0, stream, Q, K, V, PE, Out);
  }
}